// Round 1
// baseline (757.106 us; speedup 1.0000x reference)
//
#include <hip/hip_runtime.h>
#include <math.h>

#define M_NODES 20000
#define NE      320000
#define NC      4
#define NH      4
#define DIN     256
#define DOUT    128
#define DCAT    512   // NC * DOUT

// ---------------- cumsum of shared parameters ----------------
// Bu/Bi: (DIN, DCAT) concatenated cumsum weight matrices: B[k][c*128+j] = sum_{cc<=c} w[cc][k][j]
__global__ void k_cumsum_w(const float* __restrict__ w_user, const float* __restrict__ w_item,
                           float* __restrict__ Bu, float* __restrict__ Bi) {
    int idx = blockIdx.x * 256 + threadIdx.x;
    if (idx >= DIN * DOUT) return;
    int k = idx / DOUT, j = idx % DOUT;
    float su = 0.f, si = 0.f;
    for (int c = 0; c < NC; ++c) {
        su += w_user[(c * DIN + k) * DOUT + j];
        si += w_item[(c * DIN + k) * DOUT + j];
        Bu[k * DCAT + c * DOUT + j] = su;
        Bi[k * DCAT + c * DOUT + j] = si;
    }
}

// cumsum along channel axis for the 4 attention vectors, layout kept [h][c][d]
__global__ void k_cumsum_a(const float* __restrict__ aus, const float* __restrict__ aud,
                           const float* __restrict__ ais, const float* __restrict__ aid,
                           float* __restrict__ cus, float* __restrict__ cud,
                           float* __restrict__ cis, float* __restrict__ cid) {
    int idx = blockIdx.x * 256 + threadIdx.x;
    if (idx >= NH * DOUT) return;
    int h = idx / DOUT, d = idx % DOUT;
    float s0 = 0.f, s1 = 0.f, s2 = 0.f, s3 = 0.f;
    for (int c = 0; c < NC; ++c) {
        int o = (h * NC + c) * DOUT + d;
        s0 += aus[o]; s1 += aud[o]; s2 += ais[o]; s3 += aid[o];
        cus[o] = s0; cud[o] = s1; cis[o] = s2; cid[o] = s3;
    }
}

// ---------------- f32 GEMM: (Mrows x 256) @ (256 x 512) ----------------
#define BM 128
#define BN 128
#define BK 8
__global__ __launch_bounds__(256) void k_gemm(const float* __restrict__ A, const float* __restrict__ B,
                                              float* __restrict__ Cmat, int Mrows) {
    __shared__ float As[BK][BM];
    __shared__ float Bs[BK][BN];
    int m0 = blockIdx.x * BM, n0 = blockIdx.y * BN;
    int tid = threadIdx.x;
    int ty = tid >> 4, tx = tid & 15;
    float acc[8][8] = {};
    for (int k0 = 0; k0 < DIN; k0 += BK) {
        {   // A tile: 128x8, one float4 per thread, stored transposed [k][m]
            int ml = tid >> 1, k4 = (tid & 1) * 4;
            int row = m0 + ml;
            float4 v = (row < Mrows) ? *(const float4*)(A + (size_t)row * DIN + k0 + k4)
                                     : make_float4(0.f, 0.f, 0.f, 0.f);
            As[k4 + 0][ml] = v.x; As[k4 + 1][ml] = v.y;
            As[k4 + 2][ml] = v.z; As[k4 + 3][ml] = v.w;
        }
        {   // B tile: 8x128, one float4 per thread
            int kk = tid >> 5, n4 = (tid & 31) * 4;
            float4 v = *(const float4*)(B + (size_t)(k0 + kk) * DCAT + n0 + n4);
            *(float4*)(&Bs[kk][n4]) = v;
        }
        __syncthreads();
#pragma unroll
        for (int kk = 0; kk < BK; ++kk) {
            float a[8], b[8];
#pragma unroll
            for (int i = 0; i < 8; ++i) a[i] = As[kk][ty * 8 + i];
#pragma unroll
            for (int j = 0; j < 8; ++j) b[j] = Bs[kk][tx * 8 + j];
#pragma unroll
            for (int i = 0; i < 8; ++i)
#pragma unroll
                for (int j = 0; j < 8; ++j) acc[i][j] = fmaf(a[i], b[j], acc[i][j]);
        }
        __syncthreads();
    }
    for (int i = 0; i < 8; ++i) {
        int row = m0 + ty * 8 + i;
        if (row < Mrows) {
            float4 v0 = make_float4(acc[i][0], acc[i][1], acc[i][2], acc[i][3]);
            float4 v1 = make_float4(acc[i][4], acc[i][5], acc[i][6], acc[i][7]);
            *(float4*)(Cmat + (size_t)row * DCAT + n0 + tx * 8) = v0;
            *(float4*)(Cmat + (size_t)row * DCAT + n0 + tx * 8 + 4) = v1;
        }
    }
}

// ---------------- node attention scores ----------------
// s[c][m][h]: per-node dot of 128-d channel feature with cumsum'd attention vector.
// One wave per (node, side). side 0 = user (src:Aus, dst:Aid), side 1 = item (src:Ais, dst:Aud)
__global__ __launch_bounds__(256) void k_scores(const float* __restrict__ u_all, const float* __restrict__ i_all,
                                                const float* __restrict__ cus, const float* __restrict__ cud,
                                                const float* __restrict__ cis, const float* __restrict__ cid,
                                                float* __restrict__ su_src, float* __restrict__ su_dst,
                                                float* __restrict__ si_src, float* __restrict__ si_dst) {
    int wid  = (blockIdx.x * 256 + threadIdx.x) >> 6;
    int lane = threadIdx.x & 63;
    if (wid >= 2 * M_NODES) return;
    int side = wid >= M_NODES;
    int m = side ? wid - M_NODES : wid;
    const float* h    = (side ? i_all : u_all) + (size_t)m * DCAT;
    const float* Asrc = side ? cis : cus;
    const float* Adst = side ? cud : cid;
    float* Ssrc = side ? si_src : su_src;
    float* Sdst = side ? si_dst : su_dst;
    for (int c = 0; c < NC; ++c) {
        float v0 = h[c * DOUT + lane];
        float v1 = h[c * DOUT + 64 + lane];
        for (int hh = 0; hh < NH; ++hh) {
            int o = (hh * NC + c) * DOUT;
            float ps = v0 * Asrc[o + lane] + v1 * Asrc[o + 64 + lane];
            float pd = v0 * Adst[o + lane] + v1 * Adst[o + 64 + lane];
            for (int off = 32; off; off >>= 1) {
                ps += __shfl_xor(ps, off);
                pd += __shfl_xor(pd, off);
            }
            if (lane == 0) {
                Ssrc[(size_t)c * M_NODES * NH + m * NH + hh] = ps;
                Sdst[(size_t)c * M_NODES * NH + m * NH + hh] = pd;
            }
        }
    }
}

// ---------------- CSR build (8 combos: combo = c*2 + dir; dir0=u2i, dir1=i2u) ----------------
__global__ void k_zero(int* __restrict__ p, int n) {
    int i = blockIdx.x * 256 + threadIdx.x;
    if (i < n) p[i] = 0;
}

__global__ void k_count(const int* __restrict__ u2i_row, const int* __restrict__ i2u_row,
                        int* __restrict__ cnt) {
    int e = blockIdx.x * 256 + threadIdx.x;   // grid.x = NE/256 exact
    int combo = blockIdx.y, c = combo >> 1, dir = combo & 1;
    int r = dir ? i2u_row[c * NE + e] : u2i_row[c * NE + e];
    atomicAdd(cnt + combo * M_NODES + r, 1);
}

__global__ __launch_bounds__(1024) void k_scan(const int* __restrict__ cnt, int* __restrict__ off) {
    int combo = blockIdx.x, tid = threadIdx.x;
    const int CH = 20;                         // 1024*20 >= 20000
    int base = tid * CH;
    int s = 0;
    for (int k = 0; k < CH; ++k) {
        int i = base + k;
        if (i < M_NODES) s += cnt[combo * M_NODES + i];
    }
    __shared__ int part[1024];
    part[tid] = s;
    __syncthreads();
    for (int st = 1; st < 1024; st <<= 1) {
        int v = (tid >= st) ? part[tid - st] : 0;
        __syncthreads();
        part[tid] += v;
        __syncthreads();
    }
    int run = (tid == 0) ? 0 : part[tid - 1];
    for (int k = 0; k < CH; ++k) {
        int i = base + k;
        if (i < M_NODES) {
            off[combo * (M_NODES + 1) + i] = run;
            run += cnt[combo * M_NODES + i];
        }
    }
    if (tid == 1023) off[combo * (M_NODES + 1) + M_NODES] = part[1023];
}

__global__ void k_initcur(const int* __restrict__ off, int* __restrict__ cur) {
    int i = blockIdx.x * 256 + threadIdx.x;
    if (i >= 8 * M_NODES) return;
    int combo = i / M_NODES, r = i % M_NODES;
    cur[i] = off[combo * (M_NODES + 1) + r];
}

__global__ void k_fill(const int* __restrict__ u2i_row, const int* __restrict__ u2i_col,
                       const int* __restrict__ i2u_row, const int* __restrict__ i2u_col,
                       int* __restrict__ cur, int* __restrict__ cols) {
    int e = blockIdx.x * 256 + threadIdx.x;
    int combo = blockIdx.y, c = combo >> 1, dir = combo & 1;
    int r  = dir ? i2u_row[c * NE + e] : u2i_row[c * NE + e];
    int cl = dir ? i2u_col[c * NE + e] : u2i_col[c * NE + e];
    int pos = atomicAdd(cur + combo * M_NODES + r, 1);
    cols[(size_t)combo * NE + pos] = cl;
}

// ---------------- attention: one wave per output row per combo ----------------
__global__ __launch_bounds__(256) void k_attend(const float* __restrict__ u_all, const float* __restrict__ i_all,
                                                const float* __restrict__ su_src, const float* __restrict__ su_dst,
                                                const float* __restrict__ si_src, const float* __restrict__ si_dst,
                                                const int* __restrict__ off, const int* __restrict__ cols,
                                                float* __restrict__ out) {
    int combo = blockIdx.y, c = combo >> 1, dir = combo & 1;
    int wavein = threadIdx.x >> 6, lane = threadIdx.x & 63;
    int r = blockIdx.x * 4 + wavein;
    if (r >= M_NODES) return;
    const float* ssrc = (dir ? si_src : su_src) + (size_t)c * M_NODES * NH;
    const float* sdst = (dir ? su_dst : si_dst) + (size_t)c * M_NODES * NH;
    const float* hdst = (dir ? u_all : i_all) + c * DOUT;
    float* o = out + ((size_t)(dir ? M_NODES + r : r)) * DCAT + c * DOUT;
    const int* co = cols + (size_t)combo * NE;
    int s0 = off[combo * (M_NODES + 1) + r];
    int s1 = off[combo * (M_NODES + 1) + r + 1];
    int deg = s1 - s0;
    float acc0 = 0.f, acc1 = 0.f;
    if (deg > 0) {
        float4 ssv = *(const float4*)(ssrc + (size_t)r * 4);
        float ss[4] = {ssv.x, ssv.y, ssv.z, ssv.w};
        // phase 1: per-head max over the row's edges
        float mx[4] = {-1e30f, -1e30f, -1e30f, -1e30f};
        for (int base = 0; base < deg; base += 64) {
            int e = base + lane;
            float lg[4];
            if (e < deg) {
                int cl = co[s0 + e];
                float4 sdv = *(const float4*)(sdst + (size_t)cl * 4);
                float sd[4] = {sdv.x, sdv.y, sdv.z, sdv.w};
#pragma unroll
                for (int h = 0; h < 4; ++h) {
                    float x = ss[h] + sd[h];
                    lg[h] = x > 0.f ? x : 0.01f * x;
                }
            } else {
#pragma unroll
                for (int h = 0; h < 4; ++h) lg[h] = -1e30f;
            }
#pragma unroll
            for (int h = 0; h < 4; ++h) {
                float v = lg[h];
                for (int o2 = 32; o2; o2 >>= 1) v = fmaxf(v, __shfl_xor(v, o2));
                mx[h] = fmaxf(mx[h], v);
            }
        }
        // phase 2: per-head denominators
        float den[4] = {0.f, 0.f, 0.f, 0.f};
        for (int base = 0; base < deg; base += 64) {
            int e = base + lane;
            float ex[4] = {0.f, 0.f, 0.f, 0.f};
            if (e < deg) {
                int cl = co[s0 + e];
                float4 sdv = *(const float4*)(sdst + (size_t)cl * 4);
                float sd[4] = {sdv.x, sdv.y, sdv.z, sdv.w};
#pragma unroll
                for (int h = 0; h < 4; ++h) {
                    float x = ss[h] + sd[h];
                    x = x > 0.f ? x : 0.01f * x;
                    ex[h] = __expf(x - mx[h]);
                }
            }
#pragma unroll
            for (int h = 0; h < 4; ++h) {
                float v = ex[h];
                for (int o2 = 32; o2; o2 >>= 1) v += __shfl_xor(v, o2);
                den[h] += v;
            }
        }
        float inv[4];
#pragma unroll
        for (int h = 0; h < 4; ++h) inv[h] = 1.f / den[h];
        // phase 3: per-edge combined weight (sum over heads), then 128-wide gather-FMA
        for (int base = 0; base < deg; base += 64) {
            int e = base + lane;
            float w = 0.f;
            int cl = 0;
            if (e < deg) {
                cl = co[s0 + e];
                float4 sdv = *(const float4*)(sdst + (size_t)cl * 4);
                float sd[4] = {sdv.x, sdv.y, sdv.z, sdv.w};
#pragma unroll
                for (int h = 0; h < 4; ++h) {
                    float x = ss[h] + sd[h];
                    x = x > 0.f ? x : 0.01f * x;
                    w += __expf(x - mx[h]) * inv[h];
                }
            }
            int cnt2 = min(64, deg - base);
            for (int j = 0; j < cnt2; ++j) {
                float wj = __shfl(w, j);
                int   cj = __shfl(cl, j);
                const float* hp = hdst + (size_t)cj * DCAT;
                acc0 = fmaf(wj, hp[lane], acc0);
                acc1 = fmaf(wj, hp[lane + 64], acc1);
            }
        }
    }
    o[lane]      = fmaxf(acc0, 0.f);
    o[lane + 64] = fmaxf(acc1, 0.f);
}

// ---------------- launch ----------------
extern "C" void kernel_launch(void* const* d_in, const int* in_sizes, int n_in,
                              void* d_out, int out_size, void* d_ws, size_t ws_size,
                              hipStream_t stream) {
    const float* u_prev  = (const float*)d_in[0];
    const float* i_prev  = (const float*)d_in[1];
    const float* w_user  = (const float*)d_in[2];
    const float* w_item  = (const float*)d_in[3];
    const float* a_u_src = (const float*)d_in[4];
    const float* a_u_dst = (const float*)d_in[5];
    const float* a_i_src = (const float*)d_in[6];
    const float* a_i_dst = (const float*)d_in[7];
    const int* u2i_row = (const int*)d_in[8];
    const int* u2i_col = (const int*)d_in[9];
    const int* i2u_row = (const int*)d_in[10];
    const int* i2u_col = (const int*)d_in[11];
    float* out = (float*)d_out;

    char* ws = (char*)d_ws;
    size_t woff = 0;
    auto alloc = [&](size_t bytes) -> char* {
        char* p = ws + woff;
        woff += (bytes + 255) & ~(size_t)255;
        return p;
    };
    float* Bu     = (float*)alloc((size_t)DIN * DCAT * 4);
    float* Bi     = (float*)alloc((size_t)DIN * DCAT * 4);
    float* cus    = (float*)alloc((size_t)NH * NC * DOUT * 4);
    float* cud    = (float*)alloc((size_t)NH * NC * DOUT * 4);
    float* cis    = (float*)alloc((size_t)NH * NC * DOUT * 4);
    float* cid    = (float*)alloc((size_t)NH * NC * DOUT * 4);
    float* u_all  = (float*)alloc((size_t)M_NODES * DCAT * 4);
    float* i_all  = (float*)alloc((size_t)M_NODES * DCAT * 4);
    float* su_src = (float*)alloc((size_t)NC * M_NODES * NH * 4);
    float* su_dst = (float*)alloc((size_t)NC * M_NODES * NH * 4);
    float* si_src = (float*)alloc((size_t)NC * M_NODES * NH * 4);
    float* si_dst = (float*)alloc((size_t)NC * M_NODES * NH * 4);
    int* csroff   = (int*)alloc((size_t)8 * (M_NODES + 1) * 4);
    int* cnt      = (int*)alloc((size_t)8 * M_NODES * 4);        // counts, then reused as fill cursor
    int* csrcol   = (int*)alloc((size_t)8 * NE * 4);

    k_cumsum_w<<<(DIN * DOUT + 255) / 256, 256, 0, stream>>>(w_user, w_item, Bu, Bi);
    k_cumsum_a<<<(NH * DOUT + 255) / 256, 256, 0, stream>>>(a_u_src, a_u_dst, a_i_src, a_i_dst,
                                                            cus, cud, cis, cid);
    dim3 ggrid((M_NODES + BM - 1) / BM, DCAT / BN);
    k_gemm<<<ggrid, 256, 0, stream>>>(u_prev, Bu, u_all, M_NODES);
    k_gemm<<<ggrid, 256, 0, stream>>>(i_prev, Bi, i_all, M_NODES);
    k_scores<<<(2 * M_NODES + 3) / 4, 256, 0, stream>>>(u_all, i_all, cus, cud, cis, cid,
                                                        su_src, su_dst, si_src, si_dst);
    k_zero<<<(8 * M_NODES + 255) / 256, 256, 0, stream>>>(cnt, 8 * M_NODES);
    k_count<<<dim3(NE / 256, 8), 256, 0, stream>>>(u2i_row, i2u_row, cnt);
    k_scan<<<8, 1024, 0, stream>>>(cnt, csroff);
    k_initcur<<<(8 * M_NODES + 255) / 256, 256, 0, stream>>>(csroff, cnt);
    k_fill<<<dim3(NE / 256, 8), 256, 0, stream>>>(u2i_row, u2i_col, i2u_row, i2u_col, cnt, csrcol);
    k_attend<<<dim3((M_NODES + 3) / 4, 8), 256, 0, stream>>>(u_all, i_all, su_src, su_dst,
                                                             si_src, si_dst, csroff, csrcol, out);
}

// Round 2
// 689.860 us; speedup vs baseline: 1.0975x; 1.0975x over previous
//
#include <hip/hip_runtime.h>
#include <math.h>

#define M_NODES 20000
#define NE      320000
#define NC      4
#define NH      4
#define DIN     256
#define DOUT    128
#define DCAT    512   // NC * DOUT

// ---------------- cumsum of shared parameters ----------------
__global__ void k_cumsum_w(const float* __restrict__ w_user, const float* __restrict__ w_item,
                           float* __restrict__ Bu, float* __restrict__ Bi) {
    int idx = blockIdx.x * 256 + threadIdx.x;
    if (idx >= DIN * DOUT) return;
    int k = idx / DOUT, j = idx % DOUT;
    float su = 0.f, si = 0.f;
    for (int c = 0; c < NC; ++c) {
        su += w_user[(c * DIN + k) * DOUT + j];
        si += w_item[(c * DIN + k) * DOUT + j];
        Bu[k * DCAT + c * DOUT + j] = su;
        Bi[k * DCAT + c * DOUT + j] = si;
    }
}

__global__ void k_cumsum_a(const float* __restrict__ aus, const float* __restrict__ aud,
                           const float* __restrict__ ais, const float* __restrict__ aid,
                           float* __restrict__ cus, float* __restrict__ cud,
                           float* __restrict__ cis, float* __restrict__ cid) {
    int idx = blockIdx.x * 256 + threadIdx.x;
    if (idx >= NH * DOUT) return;
    int h = idx / DOUT, d = idx % DOUT;
    float s0 = 0.f, s1 = 0.f, s2 = 0.f, s3 = 0.f;
    for (int c = 0; c < NC; ++c) {
        int o = (h * NC + c) * DOUT + d;
        s0 += aus[o]; s1 += aud[o]; s2 += ais[o]; s3 += aid[o];
        cus[o] = s0; cud[o] = s1; cis[o] = s2; cid[o] = s3;
    }
}

// ---------------- f32 GEMM: (Mrows x 256) @ (256 x 512), float4 LDS fragments ----------------
#define BM 128
#define BN 128
#define BK 8
#define PAD 4
__global__ __launch_bounds__(256) void k_gemm(const float* __restrict__ A, const float* __restrict__ B,
                                              float* __restrict__ Cmat, int Mrows) {
    __shared__ float As[BK][BM + PAD];
    __shared__ float Bs[BK][BN + PAD];
    int m0 = blockIdx.x * BM, n0 = blockIdx.y * BN;
    int tid = threadIdx.x;
    int ty = tid >> 4, tx = tid & 15;
    float acc[8][8] = {};
    for (int k0 = 0; k0 < DIN; k0 += BK) {
        {   // A tile: 128x8, one float4 per thread, stored transposed [k][m]
            int ml = tid >> 1, k4 = (tid & 1) * 4;
            int row = m0 + ml;
            float4 v = (row < Mrows) ? *(const float4*)(A + (size_t)row * DIN + k0 + k4)
                                     : make_float4(0.f, 0.f, 0.f, 0.f);
            As[k4 + 0][ml] = v.x; As[k4 + 1][ml] = v.y;
            As[k4 + 2][ml] = v.z; As[k4 + 3][ml] = v.w;
        }
        {   // B tile: 8x128, one float4 per thread
            int kk = tid >> 5, n4 = (tid & 31) * 4;
            *(float4*)(&Bs[kk][n4]) = *(const float4*)(B + (size_t)(k0 + kk) * DCAT + n0 + n4);
        }
        __syncthreads();
#pragma unroll
        for (int kk = 0; kk < BK; ++kk) {
            float4 a0 = *(const float4*)(&As[kk][ty * 8]);
            float4 a1 = *(const float4*)(&As[kk][ty * 8 + 4]);
            float4 b0 = *(const float4*)(&Bs[kk][tx * 8]);
            float4 b1 = *(const float4*)(&Bs[kk][tx * 8 + 4]);
            float a[8] = {a0.x, a0.y, a0.z, a0.w, a1.x, a1.y, a1.z, a1.w};
            float b[8] = {b0.x, b0.y, b0.z, b0.w, b1.x, b1.y, b1.z, b1.w};
#pragma unroll
            for (int i = 0; i < 8; ++i)
#pragma unroll
                for (int j = 0; j < 8; ++j) acc[i][j] = fmaf(a[i], b[j], acc[i][j]);
        }
        __syncthreads();
    }
    for (int i = 0; i < 8; ++i) {
        int row = m0 + ty * 8 + i;
        if (row < Mrows) {
            float4 v0 = make_float4(acc[i][0], acc[i][1], acc[i][2], acc[i][3]);
            float4 v1 = make_float4(acc[i][4], acc[i][5], acc[i][6], acc[i][7]);
            *(float4*)(Cmat + (size_t)row * DCAT + n0 + tx * 8) = v0;
            *(float4*)(Cmat + (size_t)row * DCAT + n0 + tx * 8 + 4) = v1;
        }
    }
}

// ---------------- node attention scores ----------------
__global__ __launch_bounds__(256) void k_scores(const float* __restrict__ u_all, const float* __restrict__ i_all,
                                                const float* __restrict__ cus, const float* __restrict__ cud,
                                                const float* __restrict__ cis, const float* __restrict__ cid,
                                                float* __restrict__ su_src, float* __restrict__ su_dst,
                                                float* __restrict__ si_src, float* __restrict__ si_dst) {
    int wid  = (blockIdx.x * 256 + threadIdx.x) >> 6;
    int lane = threadIdx.x & 63;
    if (wid >= 2 * M_NODES) return;
    int side = wid >= M_NODES;
    int m = side ? wid - M_NODES : wid;
    const float* h    = (side ? i_all : u_all) + (size_t)m * DCAT;
    const float* Asrc = side ? cis : cus;
    const float* Adst = side ? cud : cid;
    float* Ssrc = side ? si_src : su_src;
    float* Sdst = side ? si_dst : su_dst;
    for (int c = 0; c < NC; ++c) {
        float v0 = h[c * DOUT + lane];
        float v1 = h[c * DOUT + 64 + lane];
        for (int hh = 0; hh < NH; ++hh) {
            int o = (hh * NC + c) * DOUT;
            float ps = v0 * Asrc[o + lane] + v1 * Asrc[o + 64 + lane];
            float pd = v0 * Adst[o + lane] + v1 * Adst[o + 64 + lane];
            for (int off = 32; off; off >>= 1) {
                ps += __shfl_xor(ps, off);
                pd += __shfl_xor(pd, off);
            }
            if (lane == 0) {
                Ssrc[(size_t)c * M_NODES * NH + m * NH + hh] = ps;
                Sdst[(size_t)c * M_NODES * NH + m * NH + hh] = pd;
            }
        }
    }
}

// ---------------- CSR build (combo = c*2 + dir; dir0=u2i, dir1=i2u) ----------------
__global__ void k_zero(int* __restrict__ p, int n) {
    int i = blockIdx.x * 256 + threadIdx.x;
    if (i < n) p[i] = 0;
}

__global__ void k_count(const int* __restrict__ u2i_row, const int* __restrict__ i2u_row,
                        int* __restrict__ cnt) {
    int e = blockIdx.x * 256 + threadIdx.x;
    int combo = blockIdx.y, c = combo >> 1, dir = combo & 1;
    int r = dir ? i2u_row[c * NE + e] : u2i_row[c * NE + e];
    atomicAdd(cnt + combo * M_NODES + r, 1);
}

__global__ __launch_bounds__(1024) void k_scan(const int* __restrict__ cnt, int* __restrict__ off) {
    int combo = blockIdx.x, tid = threadIdx.x;
    const int CH = 20;
    int base = tid * CH;
    int s = 0;
    for (int k = 0; k < CH; ++k) {
        int i = base + k;
        if (i < M_NODES) s += cnt[combo * M_NODES + i];
    }
    __shared__ int part[1024];
    part[tid] = s;
    __syncthreads();
    for (int st = 1; st < 1024; st <<= 1) {
        int v = (tid >= st) ? part[tid - st] : 0;
        __syncthreads();
        part[tid] += v;
        __syncthreads();
    }
    int run = (tid == 0) ? 0 : part[tid - 1];
    for (int k = 0; k < CH; ++k) {
        int i = base + k;
        if (i < M_NODES) {
            off[combo * (M_NODES + 1) + i] = run;
            run += cnt[combo * M_NODES + i];
        }
    }
    if (tid == 1023) off[combo * (M_NODES + 1) + M_NODES] = part[1023];
}

__global__ void k_initcur(const int* __restrict__ off, int* __restrict__ cur) {
    int i = blockIdx.x * 256 + threadIdx.x;
    if (i >= 8 * M_NODES) return;
    int combo = i / M_NODES, r = i % M_NODES;
    cur[i] = off[combo * (M_NODES + 1) + r];
}

__global__ void k_fill(const int* __restrict__ u2i_row, const int* __restrict__ u2i_col,
                       const int* __restrict__ i2u_row, const int* __restrict__ i2u_col,
                       int* __restrict__ cur, int* __restrict__ cols) {
    int e = blockIdx.x * 256 + threadIdx.x;
    int combo = blockIdx.y, c = combo >> 1, dir = combo & 1;
    int r  = dir ? i2u_row[c * NE + e] : u2i_row[c * NE + e];
    int cl = dir ? i2u_col[c * NE + e] : u2i_col[c * NE + e];
    int pos = atomicAdd(cur + combo * M_NODES + r, 1);
    cols[(size_t)combo * NE + pos] = cl;
}

// ---------------- attention: one wave per output row per combo ----------------
__global__ __launch_bounds__(256) void k_attend(const float* __restrict__ u_all, const float* __restrict__ i_all,
                                                const float* __restrict__ su_src, const float* __restrict__ su_dst,
                                                const float* __restrict__ si_src, const float* __restrict__ si_dst,
                                                const int* __restrict__ off, const int* __restrict__ cols,
                                                float* __restrict__ out) {
    int combo = blockIdx.y, c = combo >> 1, dir = combo & 1;
    int wavein = threadIdx.x >> 6, lane = threadIdx.x & 63;
    int r = blockIdx.x * 4 + wavein;
    if (r >= M_NODES) return;
    const float* ssrc = (dir ? si_src : su_src) + (size_t)c * M_NODES * NH;
    const float* sdst = (dir ? su_dst : si_dst) + (size_t)c * M_NODES * NH;
    const float* hdst = (dir ? u_all : i_all) + c * DOUT;
    float* o = out + ((size_t)(dir ? M_NODES + r : r)) * DCAT + c * DOUT;
    const int* co = cols + (size_t)combo * NE;
    int s0 = off[combo * (M_NODES + 1) + r];
    int s1 = off[combo * (M_NODES + 1) + r + 1];
    int deg = s1 - s0;

    if (deg <= 64) {
        // -------- fast path: single pass, scores in registers --------
        float4 acc = make_float4(0.f, 0.f, 0.f, 0.f);
        if (deg > 0) {
            float4 ssv = *(const float4*)(ssrc + (size_t)r * 4);
            float ss[4] = {ssv.x, ssv.y, ssv.z, ssv.w};
            int cl = 0;
            float lg[4];
            if (lane < deg) {
                cl = co[s0 + lane];
                float4 sdv = *(const float4*)(sdst + (size_t)cl * 4);
                float sd[4] = {sdv.x, sdv.y, sdv.z, sdv.w};
#pragma unroll
                for (int h = 0; h < 4; ++h) {
                    float x = ss[h] + sd[h];
                    lg[h] = x > 0.f ? x : 0.01f * x;
                }
            } else {
#pragma unroll
                for (int h = 0; h < 4; ++h) lg[h] = -1e30f;
            }
            float w = 0.f;
#pragma unroll
            for (int h = 0; h < 4; ++h) {
                float mx = lg[h];
                for (int o2 = 32; o2; o2 >>= 1) mx = fmaxf(mx, __shfl_xor(mx, o2));
                float ex = (lane < deg) ? __expf(lg[h] - mx) : 0.f;
                float den = ex;
                for (int o2 = 32; o2; o2 >>= 1) den += __shfl_xor(den, o2);
                w += ex / den;
            }
            // -------- aggregation: 2 edges per iteration, float4 gathers --------
            int half = lane >> 5, l32 = lane & 31;
            for (int j = 0; j < deg; j += 2) {
                int e = j + half;
                float we = __shfl(w, e & 63);
                int   ce = __shfl(cl, e & 63);
                if (e < deg) {
                    const float* hp = hdst + (size_t)ce * DCAT + l32 * 4;
                    float4 v = *(const float4*)hp;
                    acc.x = fmaf(we, v.x, acc.x);
                    acc.y = fmaf(we, v.y, acc.y);
                    acc.z = fmaf(we, v.z, acc.z);
                    acc.w = fmaf(we, v.w, acc.w);
                }
            }
            acc.x += __shfl_xor(acc.x, 32);
            acc.y += __shfl_xor(acc.y, 32);
            acc.z += __shfl_xor(acc.z, 32);
            acc.w += __shfl_xor(acc.w, 32);
        }
        if (lane < 32) {
            float4 rr = make_float4(fmaxf(acc.x, 0.f), fmaxf(acc.y, 0.f),
                                    fmaxf(acc.z, 0.f), fmaxf(acc.w, 0.f));
            *(float4*)(o + lane * 4) = rr;
        }
        return;
    }

    // -------- slow path (deg > 64): 3-phase, unchanged --------
    float acc0 = 0.f, acc1 = 0.f;
    {
        float4 ssv = *(const float4*)(ssrc + (size_t)r * 4);
        float ss[4] = {ssv.x, ssv.y, ssv.z, ssv.w};
        float mx[4] = {-1e30f, -1e30f, -1e30f, -1e30f};
        for (int base = 0; base < deg; base += 64) {
            int e = base + lane;
            float lg[4];
            if (e < deg) {
                int cl = co[s0 + e];
                float4 sdv = *(const float4*)(sdst + (size_t)cl * 4);
                float sd[4] = {sdv.x, sdv.y, sdv.z, sdv.w};
#pragma unroll
                for (int h = 0; h < 4; ++h) {
                    float x = ss[h] + sd[h];
                    lg[h] = x > 0.f ? x : 0.01f * x;
                }
            } else {
#pragma unroll
                for (int h = 0; h < 4; ++h) lg[h] = -1e30f;
            }
#pragma unroll
            for (int h = 0; h < 4; ++h) {
                float v = lg[h];
                for (int o2 = 32; o2; o2 >>= 1) v = fmaxf(v, __shfl_xor(v, o2));
                mx[h] = fmaxf(mx[h], v);
            }
        }
        float den[4] = {0.f, 0.f, 0.f, 0.f};
        for (int base = 0; base < deg; base += 64) {
            int e = base + lane;
            float ex[4] = {0.f, 0.f, 0.f, 0.f};
            if (e < deg) {
                int cl = co[s0 + e];
                float4 sdv = *(const float4*)(sdst + (size_t)cl * 4);
                float sd[4] = {sdv.x, sdv.y, sdv.z, sdv.w};
#pragma unroll
                for (int h = 0; h < 4; ++h) {
                    float x = ss[h] + sd[h];
                    x = x > 0.f ? x : 0.01f * x;
                    ex[h] = __expf(x - mx[h]);
                }
            }
#pragma unroll
            for (int h = 0; h < 4; ++h) {
                float v = ex[h];
                for (int o2 = 32; o2; o2 >>= 1) v += __shfl_xor(v, o2);
                den[h] += v;
            }
        }
        float inv[4];
#pragma unroll
        for (int h = 0; h < 4; ++h) inv[h] = 1.f / den[h];
        for (int base = 0; base < deg; base += 64) {
            int e = base + lane;
            float w = 0.f;
            int cl = 0;
            if (e < deg) {
                cl = co[s0 + e];
                float4 sdv = *(const float4*)(sdst + (size_t)cl * 4);
                float sd[4] = {sdv.x, sdv.y, sdv.z, sdv.w};
#pragma unroll
                for (int h = 0; h < 4; ++h) {
                    float x = ss[h] + sd[h];
                    x = x > 0.f ? x : 0.01f * x;
                    w += __expf(x - mx[h]) * inv[h];
                }
            }
            int cnt2 = min(64, deg - base);
            for (int j = 0; j < cnt2; ++j) {
                float wj = __shfl(w, j);
                int   cj = __shfl(cl, j);
                const float* hp = hdst + (size_t)cj * DCAT;
                acc0 = fmaf(wj, hp[lane], acc0);
                acc1 = fmaf(wj, hp[lane + 64], acc1);
            }
        }
    }
    o[lane]      = fmaxf(acc0, 0.f);
    o[lane + 64] = fmaxf(acc1, 0.f);
}

// ---------------- launch ----------------
extern "C" void kernel_launch(void* const* d_in, const int* in_sizes, int n_in,
                              void* d_out, int out_size, void* d_ws, size_t ws_size,
                              hipStream_t stream) {
    const float* u_prev  = (const float*)d_in[0];
    const float* i_prev  = (const float*)d_in[1];
    const float* w_user  = (const float*)d_in[2];
    const float* w_item  = (const float*)d_in[3];
    const float* a_u_src = (const float*)d_in[4];
    const float* a_u_dst = (const float*)d_in[5];
    const float* a_i_src = (const float*)d_in[6];
    const float* a_i_dst = (const float*)d_in[7];
    const int* u2i_row = (const int*)d_in[8];
    const int* u2i_col = (const int*)d_in[9];
    const int* i2u_row = (const int*)d_in[10];
    const int* i2u_col = (const int*)d_in[11];
    float* out = (float*)d_out;

    char* ws = (char*)d_ws;
    size_t woff = 0;
    auto alloc = [&](size_t bytes) -> char* {
        char* p = ws + woff;
        woff += (bytes + 255) & ~(size_t)255;
        return p;
    };
    float* Bu     = (float*)alloc((size_t)DIN * DCAT * 4);
    float* Bi     = (float*)alloc((size_t)DIN * DCAT * 4);
    float* cus    = (float*)alloc((size_t)NH * NC * DOUT * 4);
    float* cud    = (float*)alloc((size_t)NH * NC * DOUT * 4);
    float* cis    = (float*)alloc((size_t)NH * NC * DOUT * 4);
    float* cid    = (float*)alloc((size_t)NH * NC * DOUT * 4);
    float* u_all  = (float*)alloc((size_t)M_NODES * DCAT * 4);
    float* i_all  = (float*)alloc((size_t)M_NODES * DCAT * 4);
    float* su_src = (float*)alloc((size_t)NC * M_NODES * NH * 4);
    float* su_dst = (float*)alloc((size_t)NC * M_NODES * NH * 4);
    float* si_src = (float*)alloc((size_t)NC * M_NODES * NH * 4);
    float* si_dst = (float*)alloc((size_t)NC * M_NODES * NH * 4);
    int* csroff   = (int*)alloc((size_t)8 * (M_NODES + 1) * 4);
    int* cnt      = (int*)alloc((size_t)8 * M_NODES * 4);
    int* csrcol   = (int*)alloc((size_t)8 * NE * 4);

    k_cumsum_w<<<(DIN * DOUT + 255) / 256, 256, 0, stream>>>(w_user, w_item, Bu, Bi);
    k_cumsum_a<<<(NH * DOUT + 255) / 256, 256, 0, stream>>>(a_u_src, a_u_dst, a_i_src, a_i_dst,
                                                            cus, cud, cis, cid);
    dim3 ggrid((M_NODES + BM - 1) / BM, DCAT / BN);
    k_gemm<<<ggrid, 256, 0, stream>>>(u_prev, Bu, u_all, M_NODES);
    k_gemm<<<ggrid, 256, 0, stream>>>(i_prev, Bi, i_all, M_NODES);
    k_scores<<<(2 * M_NODES + 3) / 4, 256, 0, stream>>>(u_all, i_all, cus, cud, cis, cid,
                                                        su_src, su_dst, si_src, si_dst);
    k_zero<<<(8 * M_NODES + 255) / 256, 256, 0, stream>>>(cnt, 8 * M_NODES);
    k_count<<<dim3(NE / 256, 8), 256, 0, stream>>>(u2i_row, i2u_row, cnt);
    k_scan<<<8, 1024, 0, stream>>>(cnt, csroff);
    k_initcur<<<(8 * M_NODES + 255) / 256, 256, 0, stream>>>(csroff, cnt);
    k_fill<<<dim3(NE / 256, 8), 256, 0, stream>>>(u2i_row, u2i_col, i2u_row, i2u_col, cnt, csrcol);
    k_attend<<<dim3((M_NODES + 3) / 4, 8), 256, 0, stream>>>(u_all, i_all, su_src, su_dst,
                                                             si_src, si_dst, csroff, csrcol, out);
}

// Round 3
// 468.380 us; speedup vs baseline: 1.6164x; 1.4729x over previous
//
#include <hip/hip_runtime.h>
#include <math.h>

#define M_NODES 20000
#define NE      320000
#define NC      4
#define NH      4
#define DIN     256
#define DOUT    128
#define DCAT    512   // NC * DOUT

// CSR bucket-build parameters
#define RPB   256                     // rows per bucket
#define NBKT  79                      // ceil(M_NODES / RPB)
#define EPB   2048                    // edges per block (256 thr x 8)
#define NBLK  157                     // ceil(NE / EPB)
#define CAP   8192                    // LDS col staging in finalize

// ---------------- cumsum of shared parameters ----------------
__global__ void k_cumsum_w(const float* __restrict__ w_user, const float* __restrict__ w_item,
                           float* __restrict__ Bu, float* __restrict__ Bi) {
    int idx = blockIdx.x * 256 + threadIdx.x;
    if (idx >= DIN * DOUT) return;
    int k = idx / DOUT, j = idx % DOUT;
    float su = 0.f, si = 0.f;
    for (int c = 0; c < NC; ++c) {
        su += w_user[(c * DIN + k) * DOUT + j];
        si += w_item[(c * DIN + k) * DOUT + j];
        Bu[k * DCAT + c * DOUT + j] = su;
        Bi[k * DCAT + c * DOUT + j] = si;
    }
}

__global__ void k_cumsum_a(const float* __restrict__ aus, const float* __restrict__ aud,
                           const float* __restrict__ ais, const float* __restrict__ aid,
                           float* __restrict__ cus, float* __restrict__ cud,
                           float* __restrict__ cis, float* __restrict__ cid) {
    int idx = blockIdx.x * 256 + threadIdx.x;
    if (idx >= NH * DOUT) return;
    int h = idx / DOUT, d = idx % DOUT;
    float s0 = 0.f, s1 = 0.f, s2 = 0.f, s3 = 0.f;
    for (int c = 0; c < NC; ++c) {
        int o = (h * NC + c) * DOUT + d;
        s0 += aus[o]; s1 += aud[o]; s2 += ais[o]; s3 += aid[o];
        cus[o] = s0; cud[o] = s1; cis[o] = s2; cid[o] = s3;
    }
}

// ---------------- f32 GEMM: (Mrows x 256) @ (256 x 512) ----------------
#define BM 128
#define BN 128
#define BK 8
#define PAD 4
__global__ __launch_bounds__(256) void k_gemm(const float* __restrict__ A, const float* __restrict__ B,
                                              float* __restrict__ Cmat, int Mrows) {
    __shared__ float As[BK][BM + PAD];
    __shared__ float Bs[BK][BN + PAD];
    int m0 = blockIdx.x * BM, n0 = blockIdx.y * BN;
    int tid = threadIdx.x;
    int ty = tid >> 4, tx = tid & 15;
    float acc[8][8] = {};
    for (int k0 = 0; k0 < DIN; k0 += BK) {
        {
            int ml = tid >> 1, k4 = (tid & 1) * 4;
            int row = m0 + ml;
            float4 v = (row < Mrows) ? *(const float4*)(A + (size_t)row * DIN + k0 + k4)
                                     : make_float4(0.f, 0.f, 0.f, 0.f);
            As[k4 + 0][ml] = v.x; As[k4 + 1][ml] = v.y;
            As[k4 + 2][ml] = v.z; As[k4 + 3][ml] = v.w;
        }
        {
            int kk = tid >> 5, n4 = (tid & 31) * 4;
            *(float4*)(&Bs[kk][n4]) = *(const float4*)(B + (size_t)(k0 + kk) * DCAT + n0 + n4);
        }
        __syncthreads();
#pragma unroll
        for (int kk = 0; kk < BK; ++kk) {
            float4 a0 = *(const float4*)(&As[kk][ty * 8]);
            float4 a1 = *(const float4*)(&As[kk][ty * 8 + 4]);
            float4 b0 = *(const float4*)(&Bs[kk][tx * 8]);
            float4 b1 = *(const float4*)(&Bs[kk][tx * 8 + 4]);
            float a[8] = {a0.x, a0.y, a0.z, a0.w, a1.x, a1.y, a1.z, a1.w};
            float b[8] = {b0.x, b0.y, b0.z, b0.w, b1.x, b1.y, b1.z, b1.w};
#pragma unroll
            for (int i = 0; i < 8; ++i)
#pragma unroll
                for (int j = 0; j < 8; ++j) acc[i][j] = fmaf(a[i], b[j], acc[i][j]);
        }
        __syncthreads();
    }
    for (int i = 0; i < 8; ++i) {
        int row = m0 + ty * 8 + i;
        if (row < Mrows) {
            float4 v0 = make_float4(acc[i][0], acc[i][1], acc[i][2], acc[i][3]);
            float4 v1 = make_float4(acc[i][4], acc[i][5], acc[i][6], acc[i][7]);
            *(float4*)(Cmat + (size_t)row * DCAT + n0 + tx * 8) = v0;
            *(float4*)(Cmat + (size_t)row * DCAT + n0 + tx * 8 + 4) = v1;
        }
    }
}

// ---------------- node attention scores ----------------
__global__ __launch_bounds__(256) void k_scores(const float* __restrict__ u_all, const float* __restrict__ i_all,
                                                const float* __restrict__ cus, const float* __restrict__ cud,
                                                const float* __restrict__ cis, const float* __restrict__ cid,
                                                float* __restrict__ su_src, float* __restrict__ su_dst,
                                                float* __restrict__ si_src, float* __restrict__ si_dst) {
    int wid  = (blockIdx.x * 256 + threadIdx.x) >> 6;
    int lane = threadIdx.x & 63;
    if (wid >= 2 * M_NODES) return;
    int side = wid >= M_NODES;
    int m = side ? wid - M_NODES : wid;
    const float* h    = (side ? i_all : u_all) + (size_t)m * DCAT;
    const float* Asrc = side ? cis : cus;
    const float* Adst = side ? cud : cid;
    float* Ssrc = side ? si_src : su_src;
    float* Sdst = side ? si_dst : su_dst;
    for (int c = 0; c < NC; ++c) {
        float v0 = h[c * DOUT + lane];
        float v1 = h[c * DOUT + 64 + lane];
        for (int hh = 0; hh < NH; ++hh) {
            int o = (hh * NC + c) * DOUT;
            float ps = v0 * Asrc[o + lane] + v1 * Asrc[o + 64 + lane];
            float pd = v0 * Adst[o + lane] + v1 * Adst[o + 64 + lane];
            for (int off = 32; off; off >>= 1) {
                ps += __shfl_xor(ps, off);
                pd += __shfl_xor(pd, off);
            }
            if (lane == 0) {
                Ssrc[(size_t)c * M_NODES * NH + m * NH + hh] = ps;
                Sdst[(size_t)c * M_NODES * NH + m * NH + hh] = pd;
            }
        }
    }
}

// ---------------- CSR build via coarse bucketing (no global atomics) ----------------
// combo = c*2 + dir; dir0=u2i, dir1=i2u
__global__ __launch_bounds__(256) void k_bcount(const int* __restrict__ u2i_row, const int* __restrict__ i2u_row,
                                                int* __restrict__ cnt3) {
    __shared__ int hist[NBKT];
    int tid = threadIdx.x, blk = blockIdx.x, combo = blockIdx.y;
    int c = combo >> 1, dir = combo & 1;
    const int* rows = (dir ? i2u_row : u2i_row) + (size_t)c * NE;
    if (tid < NBKT) hist[tid] = 0;
    __syncthreads();
    int e0 = blk * EPB;
#pragma unroll
    for (int k = 0; k < 8; ++k) {
        int e = e0 + tid + k * 256;
        if (e < NE) atomicAdd(&hist[rows[e] >> 8], 1);
    }
    __syncthreads();
    if (tid < NBKT) cnt3[((size_t)combo * NBKT + tid) * NBLK + blk] = hist[tid];
}

// per (combo,bucket): exclusive scan of per-block counts -> block write offsets; total -> btot
__global__ void k_scanblocks(int* __restrict__ cnt3, int* __restrict__ btot) {
    int idx = blockIdx.x * 256 + threadIdx.x;
    if (idx >= 8 * NBKT) return;
    size_t base = (size_t)idx * NBLK;
    int run = 0;
    for (int b = 0; b < NBLK; ++b) {
        int v = cnt3[base + b];
        cnt3[base + b] = run;
        run += v;
    }
    btot[idx] = run;
}

// per combo: exclusive scan over bucket totals -> bucket bases (one wave per combo)
__global__ __launch_bounds__(512) void k_bbase(const int* __restrict__ btot, int* __restrict__ bbase) {
    int wave = threadIdx.x >> 6, lane = threadIdx.x & 63;
    int carry = 0;
    for (int ch = 0; ch < 2; ++ch) {
        int idx = ch * 64 + lane;
        int v = (idx < NBKT) ? btot[wave * NBKT + idx] : 0;
        int inc = v;
        for (int off = 1; off < 64; off <<= 1) {
            int t = __shfl_up(inc, off);
            if (lane >= off) inc += t;
        }
        if (idx < NBKT) bbase[wave * NBKT + idx] = carry + inc - v;
        carry += __shfl(inc, 63);
    }
}

__global__ __launch_bounds__(256) void k_bfill(const int* __restrict__ u2i_row, const int* __restrict__ u2i_col,
                                               const int* __restrict__ i2u_row, const int* __restrict__ i2u_col,
                                               const int* __restrict__ cnt3, const int* __restrict__ bbase,
                                               unsigned int* __restrict__ pairbuf) {
    __shared__ int cur[NBKT];
    int tid = threadIdx.x, blk = blockIdx.x, combo = blockIdx.y;
    int c = combo >> 1, dir = combo & 1;
    const int* rows = (dir ? i2u_row : u2i_row) + (size_t)c * NE;
    const int* cols = (dir ? i2u_col : u2i_col) + (size_t)c * NE;
    if (tid < NBKT)
        cur[tid] = bbase[combo * NBKT + tid] + cnt3[((size_t)combo * NBKT + tid) * NBLK + blk];
    __syncthreads();
    unsigned int* pb = pairbuf + (size_t)combo * NE;
    int e0 = blk * EPB;
#pragma unroll
    for (int k = 0; k < 8; ++k) {
        int e = e0 + tid + k * 256;
        if (e < NE) {
            int r = rows[e], cl = cols[e];
            int pos = atomicAdd(&cur[r >> 8], 1);
            pb[pos] = ((unsigned int)r << 16) | (unsigned int)cl;
        }
    }
}

// one block per (combo,bucket): local hist+scan, scatter cols in LDS, coalesced dump
__global__ __launch_bounds__(256) void k_finalize(const unsigned int* __restrict__ pairbuf,
                                                  const int* __restrict__ bbase, const int* __restrict__ btot,
                                                  int* __restrict__ csroff, int* __restrict__ csrcol) {
    __shared__ int hist[RPB];
    __shared__ int cur[RPB];
    __shared__ int lcol[CAP];
    int tid = threadIdx.x, bkt = blockIdx.x, combo = blockIdx.y;
    int base = bbase[combo * NBKT + bkt];
    int cntb = btot[combo * NBKT + bkt];
    const unsigned int* pb = pairbuf + (size_t)combo * NE + base;
    int* ccol = csrcol + (size_t)combo * NE + base;
    hist[tid] = 0;
    __syncthreads();
    for (int k = tid; k < cntb; k += 256)
        atomicAdd(&hist[(pb[k] >> 16) & (RPB - 1)], 1);
    __syncthreads();
    for (int st = 1; st < RPB; st <<= 1) {        // inclusive scan
        int v = (tid >= st) ? hist[tid - st] : 0;
        __syncthreads();
        hist[tid] += v;
        __syncthreads();
    }
    int ex = (tid == 0) ? 0 : hist[tid - 1];      // exclusive
    cur[tid] = ex;
    int row = bkt * RPB + tid;
    if (row < M_NODES) csroff[combo * (M_NODES + 1) + row] = base + ex;
    if (bkt == NBKT - 1 && tid == 0) csroff[combo * (M_NODES + 1) + M_NODES] = NE;
    __syncthreads();
    for (int k = tid; k < cntb; k += 256) {
        unsigned int p = pb[k];
        int rl  = (p >> 16) & (RPB - 1);
        int col = (int)(p & 0xffffu);
        int pos = atomicAdd(&cur[rl], 1);
        if (pos < CAP) lcol[pos] = col; else ccol[pos] = col;
    }
    __syncthreads();
    int lim = min(cntb, CAP);
    for (int k = tid; k < lim; k += 256) ccol[k] = lcol[k];
}

// ---------------- attention: one wave per output row per combo ----------------
__global__ __launch_bounds__(256) void k_attend(const float* __restrict__ u_all, const float* __restrict__ i_all,
                                                const float* __restrict__ su_src, const float* __restrict__ su_dst,
                                                const float* __restrict__ si_src, const float* __restrict__ si_dst,
                                                const int* __restrict__ off, const int* __restrict__ cols,
                                                float* __restrict__ out) {
    int combo = blockIdx.y, c = combo >> 1, dir = combo & 1;
    int wavein = threadIdx.x >> 6, lane = threadIdx.x & 63;
    int r = blockIdx.x * 4 + wavein;
    if (r >= M_NODES) return;
    const float* ssrc = (dir ? si_src : su_src) + (size_t)c * M_NODES * NH;
    const float* sdst = (dir ? su_dst : si_dst) + (size_t)c * M_NODES * NH;
    const float* hdst = (dir ? u_all : i_all) + c * DOUT;
    float* o = out + ((size_t)(dir ? M_NODES + r : r)) * DCAT + c * DOUT;
    const int* co = cols + (size_t)combo * NE;
    int s0 = off[combo * (M_NODES + 1) + r];
    int s1 = off[combo * (M_NODES + 1) + r + 1];
    int deg = s1 - s0;

    if (deg <= 64) {
        float4 acc = make_float4(0.f, 0.f, 0.f, 0.f);
        if (deg > 0) {
            float4 ssv = *(const float4*)(ssrc + (size_t)r * 4);
            float ss[4] = {ssv.x, ssv.y, ssv.z, ssv.w};
            int cl = 0;
            float lg[4];
            if (lane < deg) {
                cl = co[s0 + lane];
                float4 sdv = *(const float4*)(sdst + (size_t)cl * 4);
                float sd[4] = {sdv.x, sdv.y, sdv.z, sdv.w};
#pragma unroll
                for (int h = 0; h < 4; ++h) {
                    float x = ss[h] + sd[h];
                    lg[h] = x > 0.f ? x : 0.01f * x;
                }
            } else {
#pragma unroll
                for (int h = 0; h < 4; ++h) lg[h] = -1e30f;
            }
            float w = 0.f;
#pragma unroll
            for (int h = 0; h < 4; ++h) {
                float mx = lg[h];
                for (int o2 = 32; o2; o2 >>= 1) mx = fmaxf(mx, __shfl_xor(mx, o2));
                float ex = (lane < deg) ? __expf(lg[h] - mx) : 0.f;
                float den = ex;
                for (int o2 = 32; o2; o2 >>= 1) den += __shfl_xor(den, o2);
                w += ex / den;
            }
            int half = lane >> 5, l32 = lane & 31;
            for (int j = 0; j < deg; j += 2) {
                int e = j + half;
                float we = __shfl(w, e & 63);
                int   ce = __shfl(cl, e & 63);
                if (e < deg) {
                    const float* hp = hdst + (size_t)ce * DCAT + l32 * 4;
                    float4 v = *(const float4*)hp;
                    acc.x = fmaf(we, v.x, acc.x);
                    acc.y = fmaf(we, v.y, acc.y);
                    acc.z = fmaf(we, v.z, acc.z);
                    acc.w = fmaf(we, v.w, acc.w);
                }
            }
            acc.x += __shfl_xor(acc.x, 32);
            acc.y += __shfl_xor(acc.y, 32);
            acc.z += __shfl_xor(acc.z, 32);
            acc.w += __shfl_xor(acc.w, 32);
        }
        if (lane < 32) {
            float4 rr = make_float4(fmaxf(acc.x, 0.f), fmaxf(acc.y, 0.f),
                                    fmaxf(acc.z, 0.f), fmaxf(acc.w, 0.f));
            *(float4*)(o + lane * 4) = rr;
        }
        return;
    }

    // slow path (deg > 64)
    float acc0 = 0.f, acc1 = 0.f;
    {
        float4 ssv = *(const float4*)(ssrc + (size_t)r * 4);
        float ss[4] = {ssv.x, ssv.y, ssv.z, ssv.w};
        float mx[4] = {-1e30f, -1e30f, -1e30f, -1e30f};
        for (int base = 0; base < deg; base += 64) {
            int e = base + lane;
            float lg[4];
            if (e < deg) {
                int cl = co[s0 + e];
                float4 sdv = *(const float4*)(sdst + (size_t)cl * 4);
                float sd[4] = {sdv.x, sdv.y, sdv.z, sdv.w};
#pragma unroll
                for (int h = 0; h < 4; ++h) {
                    float x = ss[h] + sd[h];
                    lg[h] = x > 0.f ? x : 0.01f * x;
                }
            } else {
#pragma unroll
                for (int h = 0; h < 4; ++h) lg[h] = -1e30f;
            }
#pragma unroll
            for (int h = 0; h < 4; ++h) {
                float v = lg[h];
                for (int o2 = 32; o2; o2 >>= 1) v = fmaxf(v, __shfl_xor(v, o2));
                mx[h] = fmaxf(mx[h], v);
            }
        }
        float den[4] = {0.f, 0.f, 0.f, 0.f};
        for (int base = 0; base < deg; base += 64) {
            int e = base + lane;
            float ex[4] = {0.f, 0.f, 0.f, 0.f};
            if (e < deg) {
                int cl = co[s0 + e];
                float4 sdv = *(const float4*)(sdst + (size_t)cl * 4);
                float sd[4] = {sdv.x, sdv.y, sdv.z, sdv.w};
#pragma unroll
                for (int h = 0; h < 4; ++h) {
                    float x = ss[h] + sd[h];
                    x = x > 0.f ? x : 0.01f * x;
                    ex[h] = __expf(x - mx[h]);
                }
            }
#pragma unroll
            for (int h = 0; h < 4; ++h) {
                float v = ex[h];
                for (int o2 = 32; o2; o2 >>= 1) v += __shfl_xor(v, o2);
                den[h] += v;
            }
        }
        float inv[4];
#pragma unroll
        for (int h = 0; h < 4; ++h) inv[h] = 1.f / den[h];
        for (int base = 0; base < deg; base += 64) {
            int e = base + lane;
            float w = 0.f;
            int cl = 0;
            if (e < deg) {
                cl = co[s0 + e];
                float4 sdv = *(const float4*)(sdst + (size_t)cl * 4);
                float sd[4] = {sdv.x, sdv.y, sdv.z, sdv.w};
#pragma unroll
                for (int h = 0; h < 4; ++h) {
                    float x = ss[h] + sd[h];
                    x = x > 0.f ? x : 0.01f * x;
                    w += __expf(x - mx[h]) * inv[h];
                }
            }
            int cnt2 = min(64, deg - base);
            for (int j = 0; j < cnt2; ++j) {
                float wj = __shfl(w, j);
                int   cj = __shfl(cl, j);
                const float* hp = hdst + (size_t)cj * DCAT;
                acc0 = fmaf(wj, hp[lane], acc0);
                acc1 = fmaf(wj, hp[lane + 64], acc1);
            }
        }
    }
    o[lane]      = fmaxf(acc0, 0.f);
    o[lane + 64] = fmaxf(acc1, 0.f);
}

// ---------------- launch ----------------
extern "C" void kernel_launch(void* const* d_in, const int* in_sizes, int n_in,
                              void* d_out, int out_size, void* d_ws, size_t ws_size,
                              hipStream_t stream) {
    const float* u_prev  = (const float*)d_in[0];
    const float* i_prev  = (const float*)d_in[1];
    const float* w_user  = (const float*)d_in[2];
    const float* w_item  = (const float*)d_in[3];
    const float* a_u_src = (const float*)d_in[4];
    const float* a_u_dst = (const float*)d_in[5];
    const float* a_i_src = (const float*)d_in[6];
    const float* a_i_dst = (const float*)d_in[7];
    const int* u2i_row = (const int*)d_in[8];
    const int* u2i_col = (const int*)d_in[9];
    const int* i2u_row = (const int*)d_in[10];
    const int* i2u_col = (const int*)d_in[11];
    float* out = (float*)d_out;

    char* ws = (char*)d_ws;
    size_t woff = 0;
    auto alloc = [&](size_t bytes) -> char* {
        char* p = ws + woff;
        woff += (bytes + 255) & ~(size_t)255;
        return p;
    };
    float* Bu     = (float*)alloc((size_t)DIN * DCAT * 4);
    float* Bi     = (float*)alloc((size_t)DIN * DCAT * 4);
    float* cus    = (float*)alloc((size_t)NH * NC * DOUT * 4);
    float* cud    = (float*)alloc((size_t)NH * NC * DOUT * 4);
    float* cis    = (float*)alloc((size_t)NH * NC * DOUT * 4);
    float* cid    = (float*)alloc((size_t)NH * NC * DOUT * 4);
    float* u_all  = (float*)alloc((size_t)M_NODES * DCAT * 4);
    float* i_all  = (float*)alloc((size_t)M_NODES * DCAT * 4);
    float* su_src = (float*)alloc((size_t)NC * M_NODES * NH * 4);
    float* su_dst = (float*)alloc((size_t)NC * M_NODES * NH * 4);
    float* si_src = (float*)alloc((size_t)NC * M_NODES * NH * 4);
    float* si_dst = (float*)alloc((size_t)NC * M_NODES * NH * 4);
    int* csroff   = (int*)alloc((size_t)8 * (M_NODES + 1) * 4);
    int* csrcol   = (int*)alloc((size_t)8 * NE * 4);
    int* cnt3     = (int*)alloc((size_t)8 * NBKT * NBLK * 4);
    int* btot     = (int*)alloc((size_t)8 * NBKT * 4);
    int* bbase    = (int*)alloc((size_t)8 * NBKT * 4);
    unsigned int* pairbuf = (unsigned int*)alloc((size_t)8 * NE * 4);

    k_cumsum_w<<<(DIN * DOUT + 255) / 256, 256, 0, stream>>>(w_user, w_item, Bu, Bi);
    k_cumsum_a<<<(NH * DOUT + 255) / 256, 256, 0, stream>>>(a_u_src, a_u_dst, a_i_src, a_i_dst,
                                                            cus, cud, cis, cid);
    dim3 ggrid((M_NODES + BM - 1) / BM, DCAT / BN);
    k_gemm<<<ggrid, 256, 0, stream>>>(u_prev, Bu, u_all, M_NODES);
    k_gemm<<<ggrid, 256, 0, stream>>>(i_prev, Bi, i_all, M_NODES);
    k_scores<<<(2 * M_NODES + 3) / 4, 256, 0, stream>>>(u_all, i_all, cus, cud, cis, cid,
                                                        su_src, su_dst, si_src, si_dst);
    k_bcount<<<dim3(NBLK, 8), 256, 0, stream>>>(u2i_row, i2u_row, cnt3);
    k_scanblocks<<<(8 * NBKT + 255) / 256, 256, 0, stream>>>(cnt3, btot);
    k_bbase<<<1, 512, 0, stream>>>(btot, bbase);
    k_bfill<<<dim3(NBLK, 8), 256, 0, stream>>>(u2i_row, u2i_col, i2u_row, i2u_col, cnt3, bbase, pairbuf);
    k_finalize<<<dim3(NBKT, 8), 256, 0, stream>>>(pairbuf, bbase, btot, csroff, csrcol);
    k_attend<<<dim3((M_NODES + 3) / 4, 8), 256, 0, stream>>>(u_all, i_all, su_src, su_dst,
                                                             si_src, si_dst, csroff, csrcol, out);
}

// Round 4
// 368.710 us; speedup vs baseline: 2.0534x; 1.2703x over previous
//
#include <hip/hip_runtime.h>
#include <math.h>

#define M_NODES 20000
#define NE      320000
#define NC      4
#define NH      4
#define DIN     256
#define DOUT    128
#define DCAT    512   // NC * DOUT

// CSR bucket-build parameters
#define RPB   256
#define NBKT  79
#define EPB   2048
#define NBLK  157
#define CAP   8192

typedef __attribute__((ext_vector_type(8))) short short8v;
typedef __attribute__((ext_vector_type(4))) float f32x4;

__device__ __forceinline__ unsigned short f2bf(float x) {
    unsigned int u = __float_as_uint(x);
    unsigned int r = u + 0x7fffu + ((u >> 16) & 1u);
    return (unsigned short)(r >> 16);
}
__device__ __forceinline__ float bf2f(unsigned short h) {
    return __uint_as_float((unsigned int)h << 16);
}

// ---------------- A split: f32 (20000x256) -> [A_hi | A_lo] bf16 (20000x512) ----------------
__global__ __launch_bounds__(256) void k_splitA(const float* __restrict__ u_prev, const float* __restrict__ i_prev,
                                                unsigned short* __restrict__ AbigU, unsigned short* __restrict__ AbigI) {
    int t = blockIdx.x * 256 + threadIdx.x;      // 20000*32 threads
    if (t >= M_NODES * 32) return;
    int row = t >> 5, kc = (t & 31) * 8;
    const float* src = blockIdx.y ? i_prev : u_prev;
    unsigned short* dst = blockIdx.y ? AbigI : AbigU;
    float4 x0 = *(const float4*)(src + (size_t)row * DIN + kc);
    float4 x1 = *(const float4*)(src + (size_t)row * DIN + kc + 4);
    float xs[8] = {x0.x, x0.y, x0.z, x0.w, x1.x, x1.y, x1.z, x1.w};
    unsigned int H[4], L[4];
#pragma unroll
    for (int p = 0; p < 4; ++p) {
        unsigned short h0 = f2bf(xs[2 * p]);
        unsigned short h1 = f2bf(xs[2 * p + 1]);
        unsigned short l0 = f2bf(xs[2 * p] - bf2f(h0));
        unsigned short l1 = f2bf(xs[2 * p + 1] - bf2f(h1));
        H[p] = (unsigned int)h0 | ((unsigned int)h1 << 16);
        L[p] = (unsigned int)l0 | ((unsigned int)l1 << 16);
    }
    *(uint4*)(dst + (size_t)row * 512 + kc)       = make_uint4(H[0], H[1], H[2], H[3]);
    *(uint4*)(dst + (size_t)row * 512 + 256 + kc) = make_uint4(L[0], L[1], L[2], L[3]);
}

// ---------------- B prep: cumsum + split + transpose -> BT [512(n)][768(k)] bf16 ----------------
// k rows 0-255: B_hi ; 256-511: B_lo ; 512-767: B_hi   (pairs with A cols: hi, hi, lo)
__global__ __launch_bounds__(256) void k_prepB(const float* __restrict__ w_user, const float* __restrict__ w_item,
                                               unsigned short* __restrict__ BTu, unsigned short* __restrict__ BTi) {
    int idx = blockIdx.x * 256 + threadIdx.x;    // 256*128
    if (idx >= DIN * DOUT) return;
    int k = idx >> 7, j = idx & 127;
    float su = 0.f, si = 0.f;
    for (int c = 0; c < NC; ++c) {
        su += w_user[((size_t)c * DIN + k) * DOUT + j];
        si += w_item[((size_t)c * DIN + k) * DOUT + j];
        size_t n = (size_t)(c * DOUT + j) * 768;
        unsigned short hu = f2bf(su), hi2 = f2bf(si);
        unsigned short lu = f2bf(su - bf2f(hu)), li = f2bf(si - bf2f(hi2));
        BTu[n + k] = hu;  BTu[n + 256 + k] = lu;  BTu[n + 512 + k] = hu;
        BTi[n + k] = hi2; BTi[n + 256 + k] = li;  BTi[n + 512 + k] = hi2;
    }
}

// cumsum along channel axis for attention vectors (f32)
__global__ void k_cumsum_a(const float* __restrict__ aus, const float* __restrict__ aud,
                           const float* __restrict__ ais, const float* __restrict__ aid,
                           float* __restrict__ cus, float* __restrict__ cud,
                           float* __restrict__ cis, float* __restrict__ cid) {
    int idx = blockIdx.x * 256 + threadIdx.x;
    if (idx >= NH * DOUT) return;
    int h = idx / DOUT, d = idx % DOUT;
    float s0 = 0.f, s1 = 0.f, s2 = 0.f, s3 = 0.f;
    for (int c = 0; c < NC; ++c) {
        int o = (h * NC + c) * DOUT + d;
        s0 += aus[o]; s1 += aud[o]; s2 += ais[o]; s3 += aid[o];
        cus[o] = s0; cud[o] = s1; cis[o] = s2; cid[o] = s3;
    }
}

// ---------------- MFMA GEMM: (20000x512 bf16 split) @ BT(512x768) -> fb [4][20000][128] bf16 ----------------
#define LDK 88
__global__ __launch_bounds__(256) void k_gmm(const unsigned short* __restrict__ Abig,
                                             const unsigned short* __restrict__ BT,
                                             unsigned short* __restrict__ fb) {
    __shared__ unsigned short As[128 * LDK];
    __shared__ unsigned short Bs[128 * LDK];
    int m0 = blockIdx.x * 128;
    int c  = blockIdx.y;                 // output channel == n-tile (128 cols each)
    int tid = threadIdx.x;
    int w = tid >> 6, lane = tid & 63;
    int wrb = (w >> 1) * 64, wcb = (w & 1) * 64;
    int l15 = lane & 15, g = lane >> 4;
    f32x4 acc[4][4] = {};
    int rr = tid >> 3, kc = (tid & 7) * 8;
    for (int kt = 0; kt < 12; ++kt) {
        int k0 = kt * 64;
        int acol0 = (k0 < 256) ? k0 : k0 - 256;   // k>=512 maps to A_lo (cols 256-511)
#pragma unroll
        for (int p = 0; p < 4; ++p) {
            int row = p * 32 + rr;
            uint4 v = make_uint4(0u, 0u, 0u, 0u);
            if (m0 + row < M_NODES)
                v = *(const uint4*)(Abig + (size_t)(m0 + row) * 512 + acol0 + kc);
            *(uint4*)(&As[row * LDK + kc]) = v;
        }
#pragma unroll
        for (int p = 0; p < 4; ++p) {
            int nn = p * 32 + rr;
            uint4 v = *(const uint4*)(BT + (size_t)(c * 128 + nn) * 768 + k0 + kc);
            *(uint4*)(&Bs[nn * LDK + kc]) = v;
        }
        __syncthreads();
#pragma unroll
        for (int ks = 0; ks < 2; ++ks) {
            short8v a[4], b[4];
#pragma unroll
            for (int i = 0; i < 4; ++i)
                a[i] = *(const short8v*)(&As[(wrb + i * 16 + l15) * LDK + ks * 32 + g * 8]);
#pragma unroll
            for (int j = 0; j < 4; ++j)
                b[j] = *(const short8v*)(&Bs[(wcb + j * 16 + l15) * LDK + ks * 32 + g * 8]);
#pragma unroll
            for (int i = 0; i < 4; ++i)
#pragma unroll
                for (int j = 0; j < 4; ++j)
                    acc[i][j] = __builtin_amdgcn_mfma_f32_16x16x32_bf16(a[i], b[j], acc[i][j], 0, 0, 0);
        }
        __syncthreads();
    }
#pragma unroll
    for (int i = 0; i < 4; ++i) {
#pragma unroll
        for (int r = 0; r < 4; ++r) {
            int node = m0 + wrb + i * 16 + g * 4 + r;
            if (node < M_NODES) {
#pragma unroll
                for (int j = 0; j < 4; ++j) {
                    int d = wcb + j * 16 + l15;
                    fb[((size_t)c * M_NODES + node) * DOUT + d] = f2bf(acc[i][j][r]);
                }
            }
        }
    }
}

// ---------------- node attention scores (from bf16 feature tables) ----------------
__global__ __launch_bounds__(256) void k_scores(const unsigned short* __restrict__ fbu, const unsigned short* __restrict__ fbi,
                                                const float* __restrict__ cus, const float* __restrict__ cud,
                                                const float* __restrict__ cis, const float* __restrict__ cid,
                                                float* __restrict__ su_src, float* __restrict__ su_dst,
                                                float* __restrict__ si_src, float* __restrict__ si_dst) {
    int wid  = (blockIdx.x * 256 + threadIdx.x) >> 6;
    int lane = threadIdx.x & 63;
    if (wid >= 2 * M_NODES) return;
    int side = wid >= M_NODES;
    int m = side ? wid - M_NODES : wid;
    const unsigned short* fb = side ? fbi : fbu;
    const float* Asrc = side ? cis : cus;
    const float* Adst = side ? cud : cid;
    float* Ssrc = side ? si_src : su_src;
    float* Sdst = side ? si_dst : su_dst;
    for (int c = 0; c < NC; ++c) {
        unsigned int hv = *(const unsigned int*)(fb + ((size_t)c * M_NODES + m) * DOUT + lane * 2);
        float v0 = __uint_as_float(hv << 16);
        float v1 = __uint_as_float(hv & 0xffff0000u);
        for (int hh = 0; hh < NH; ++hh) {
            int o = (hh * NC + c) * DOUT;
            float ps = v0 * Asrc[o + lane * 2] + v1 * Asrc[o + lane * 2 + 1];
            float pd = v0 * Adst[o + lane * 2] + v1 * Adst[o + lane * 2 + 1];
            for (int off = 32; off; off >>= 1) {
                ps += __shfl_xor(ps, off);
                pd += __shfl_xor(pd, off);
            }
            if (lane == 0) {
                Ssrc[(size_t)c * M_NODES * NH + m * NH + hh] = ps;
                Sdst[(size_t)c * M_NODES * NH + m * NH + hh] = pd;
            }
        }
    }
}

// ---------------- CSR build via coarse bucketing ----------------
__global__ __launch_bounds__(256) void k_bcount(const int* __restrict__ u2i_row, const int* __restrict__ i2u_row,
                                                int* __restrict__ cnt3) {
    __shared__ int hist[NBKT];
    int tid = threadIdx.x, blk = blockIdx.x, combo = blockIdx.y;
    int c = combo >> 1, dir = combo & 1;
    const int* rows = (dir ? i2u_row : u2i_row) + (size_t)c * NE;
    if (tid < NBKT) hist[tid] = 0;
    __syncthreads();
    int e0 = blk * EPB;
#pragma unroll
    for (int k = 0; k < 8; ++k) {
        int e = e0 + tid + k * 256;
        if (e < NE) atomicAdd(&hist[rows[e] >> 8], 1);
    }
    __syncthreads();
    if (tid < NBKT) cnt3[((size_t)combo * NBKT + tid) * NBLK + blk] = hist[tid];
}

__global__ void k_scanblocks(int* __restrict__ cnt3, int* __restrict__ btot) {
    int idx = blockIdx.x * 256 + threadIdx.x;
    if (idx >= 8 * NBKT) return;
    size_t base = (size_t)idx * NBLK;
    int run = 0;
    for (int b = 0; b < NBLK; ++b) {
        int v = cnt3[base + b];
        cnt3[base + b] = run;
        run += v;
    }
    btot[idx] = run;
}

__global__ __launch_bounds__(512) void k_bbase(const int* __restrict__ btot, int* __restrict__ bbase) {
    int wave = threadIdx.x >> 6, lane = threadIdx.x & 63;
    int carry = 0;
    for (int ch = 0; ch < 2; ++ch) {
        int idx = ch * 64 + lane;
        int v = (idx < NBKT) ? btot[wave * NBKT + idx] : 0;
        int inc = v;
        for (int off = 1; off < 64; off <<= 1) {
            int t = __shfl_up(inc, off);
            if (lane >= off) inc += t;
        }
        if (idx < NBKT) bbase[wave * NBKT + idx] = carry + inc - v;
        carry += __shfl(inc, 63);
    }
}

__global__ __launch_bounds__(256) void k_bfill(const int* __restrict__ u2i_row, const int* __restrict__ u2i_col,
                                               const int* __restrict__ i2u_row, const int* __restrict__ i2u_col,
                                               const int* __restrict__ cnt3, const int* __restrict__ bbase,
                                               unsigned int* __restrict__ pairbuf) {
    __shared__ int cur[NBKT];
    int tid = threadIdx.x, blk = blockIdx.x, combo = blockIdx.y;
    int c = combo >> 1, dir = combo & 1;
    const int* rows = (dir ? i2u_row : u2i_row) + (size_t)c * NE;
    const int* cols = (dir ? i2u_col : u2i_col) + (size_t)c * NE;
    if (tid < NBKT)
        cur[tid] = bbase[combo * NBKT + tid] + cnt3[((size_t)combo * NBKT + tid) * NBLK + blk];
    __syncthreads();
    unsigned int* pb = pairbuf + (size_t)combo * NE;
    int e0 = blk * EPB;
#pragma unroll
    for (int k = 0; k < 8; ++k) {
        int e = e0 + tid + k * 256;
        if (e < NE) {
            int r = rows[e], cl = cols[e];
            int pos = atomicAdd(&cur[r >> 8], 1);
            pb[pos] = ((unsigned int)r << 16) | (unsigned int)cl;
        }
    }
}

__global__ __launch_bounds__(256) void k_finalize(const unsigned int* __restrict__ pairbuf,
                                                  const int* __restrict__ bbase, const int* __restrict__ btot,
                                                  int* __restrict__ csroff, int* __restrict__ csrcol) {
    __shared__ int hist[RPB];
    __shared__ int cur[RPB];
    __shared__ int lcol[CAP];
    int tid = threadIdx.x, bkt = blockIdx.x, combo = blockIdx.y;
    int base = bbase[combo * NBKT + bkt];
    int cntb = btot[combo * NBKT + bkt];
    const unsigned int* pb = pairbuf + (size_t)combo * NE + base;
    int* ccol = csrcol + (size_t)combo * NE + base;
    hist[tid] = 0;
    __syncthreads();
    for (int k = tid; k < cntb; k += 256)
        atomicAdd(&hist[(pb[k] >> 16) & (RPB - 1)], 1);
    __syncthreads();
    for (int st = 1; st < RPB; st <<= 1) {
        int v = (tid >= st) ? hist[tid - st] : 0;
        __syncthreads();
        hist[tid] += v;
        __syncthreads();
    }
    int ex = (tid == 0) ? 0 : hist[tid - 1];
    cur[tid] = ex;
    int row = bkt * RPB + tid;
    if (row < M_NODES) csroff[combo * (M_NODES + 1) + row] = base + ex;
    if (bkt == NBKT - 1 && tid == 0) csroff[combo * (M_NODES + 1) + M_NODES] = NE;
    __syncthreads();
    for (int k = tid; k < cntb; k += 256) {
        unsigned int p = pb[k];
        int rl  = (p >> 16) & (RPB - 1);
        int col = (int)(p & 0xffffu);
        int pos = atomicAdd(&cur[rl], 1);
        if (pos < CAP) lcol[pos] = col; else ccol[pos] = col;
    }
    __syncthreads();
    int lim = min(cntb, CAP);
    for (int k = tid; k < lim; k += 256) ccol[k] = lcol[k];
}

// ---------------- attention: one wave per output row per combo, bf16 gathers ----------------
__global__ __launch_bounds__(256) void k_attend(const unsigned short* __restrict__ fbu, const unsigned short* __restrict__ fbi,
                                                const float* __restrict__ su_src, const float* __restrict__ su_dst,
                                                const float* __restrict__ si_src, const float* __restrict__ si_dst,
                                                const int* __restrict__ off, const int* __restrict__ cols,
                                                float* __restrict__ out) {
    int combo = blockIdx.y, c = combo >> 1, dir = combo & 1;
    int wavein = threadIdx.x >> 6, lane = threadIdx.x & 63;
    int r = blockIdx.x * 4 + wavein;
    if (r >= M_NODES) return;
    const float* ssrc = (dir ? si_src : su_src) + (size_t)c * M_NODES * NH;
    const float* sdst = (dir ? su_dst : si_dst) + (size_t)c * M_NODES * NH;
    const unsigned short* fbd = (dir ? fbu : fbi) + (size_t)c * M_NODES * DOUT;
    float* o = out + ((size_t)(dir ? M_NODES + r : r)) * DCAT + c * DOUT;
    const int* co = cols + (size_t)combo * NE;
    int s0 = off[combo * (M_NODES + 1) + r];
    int s1 = off[combo * (M_NODES + 1) + r + 1];
    int deg = s1 - s0;

    if (deg <= 64) {
        float w = 0.f;
        int cl = 0;
        if (deg > 0) {
            float4 ssv = *(const float4*)(ssrc + (size_t)r * 4);
            float ss[4] = {ssv.x, ssv.y, ssv.z, ssv.w};
            float lg[4];
            if (lane < deg) {
                cl = co[s0 + lane];
                float4 sdv = *(const float4*)(sdst + (size_t)cl * 4);
                float sd[4] = {sdv.x, sdv.y, sdv.z, sdv.w};
#pragma unroll
                for (int h = 0; h < 4; ++h) {
                    float x = ss[h] + sd[h];
                    lg[h] = x > 0.f ? x : 0.01f * x;
                }
            } else {
#pragma unroll
                for (int h = 0; h < 4; ++h) lg[h] = -1e30f;
            }
#pragma unroll
            for (int h = 0; h < 4; ++h) {
                float mx = lg[h];
                for (int o2 = 32; o2; o2 >>= 1) mx = fmaxf(mx, __shfl_xor(mx, o2));
                float ex = (lane < deg) ? __expf(lg[h] - mx) : 0.f;
                float den = ex;
                for (int o2 = 32; o2; o2 >>= 1) den += __shfl_xor(den, o2);
                w += ex / den;
            }
        }
        // aggregation: 4 edges/iter, 16 lanes x 16B (8 bf16) each
        int q = lane >> 4, l16 = lane & 15;
        float a8[8] = {};
        for (int j = 0; j < deg; j += 4) {
            int e = j + q;
            float we = __shfl(w, e & 63);
            int   ce = __shfl(cl, e & 63);
            if (e < deg) {
                uint4 v = *(const uint4*)(fbd + (size_t)ce * DOUT + l16 * 8);
                a8[0] = fmaf(we, __uint_as_float(v.x << 16), a8[0]);
                a8[1] = fmaf(we, __uint_as_float(v.x & 0xffff0000u), a8[1]);
                a8[2] = fmaf(we, __uint_as_float(v.y << 16), a8[2]);
                a8[3] = fmaf(we, __uint_as_float(v.y & 0xffff0000u), a8[3]);
                a8[4] = fmaf(we, __uint_as_float(v.z << 16), a8[4]);
                a8[5] = fmaf(we, __uint_as_float(v.z & 0xffff0000u), a8[5]);
                a8[6] = fmaf(we, __uint_as_float(v.w << 16), a8[6]);
                a8[7] = fmaf(we, __uint_as_float(v.w & 0xffff0000u), a8[7]);
            }
        }
#pragma unroll
        for (int i = 0; i < 8; ++i) {
            a8[i] += __shfl_xor(a8[i], 16);
            a8[i] += __shfl_xor(a8[i], 32);
        }
        if (lane < 16) {
            float4 r0 = make_float4(fmaxf(a8[0], 0.f), fmaxf(a8[1], 0.f), fmaxf(a8[2], 0.f), fmaxf(a8[3], 0.f));
            float4 r1 = make_float4(fmaxf(a8[4], 0.f), fmaxf(a8[5], 0.f), fmaxf(a8[6], 0.f), fmaxf(a8[7], 0.f));
            *(float4*)(o + l16 * 8) = r0;
            *(float4*)(o + l16 * 8 + 4) = r1;
        }
        return;
    }

    // slow path (deg > 64): 3-phase, bf16 gathers, 2 dims/lane
    float acc0 = 0.f, acc1 = 0.f;
    {
        float4 ssv = *(const float4*)(ssrc + (size_t)r * 4);
        float ss[4] = {ssv.x, ssv.y, ssv.z, ssv.w};
        float mx[4] = {-1e30f, -1e30f, -1e30f, -1e30f};
        for (int base = 0; base < deg; base += 64) {
            int e = base + lane;
            float lg[4];
            if (e < deg) {
                int cl = co[s0 + e];
                float4 sdv = *(const float4*)(sdst + (size_t)cl * 4);
                float sd[4] = {sdv.x, sdv.y, sdv.z, sdv.w};
#pragma unroll
                for (int h = 0; h < 4; ++h) {
                    float x = ss[h] + sd[h];
                    lg[h] = x > 0.f ? x : 0.01f * x;
                }
            } else {
#pragma unroll
                for (int h = 0; h < 4; ++h) lg[h] = -1e30f;
            }
#pragma unroll
            for (int h = 0; h < 4; ++h) {
                float v = lg[h];
                for (int o2 = 32; o2; o2 >>= 1) v = fmaxf(v, __shfl_xor(v, o2));
                mx[h] = fmaxf(mx[h], v);
            }
        }
        float den[4] = {0.f, 0.f, 0.f, 0.f};
        for (int base = 0; base < deg; base += 64) {
            int e = base + lane;
            float ex[4] = {0.f, 0.f, 0.f, 0.f};
            if (e < deg) {
                int cl = co[s0 + e];
                float4 sdv = *(const float4*)(sdst + (size_t)cl * 4);
                float sd[4] = {sdv.x, sdv.y, sdv.z, sdv.w};
#pragma unroll
                for (int h = 0; h < 4; ++h) {
                    float x = ss[h] + sd[h];
                    x = x > 0.f ? x : 0.01f * x;
                    ex[h] = __expf(x - mx[h]);
                }
            }
#pragma unroll
            for (int h = 0; h < 4; ++h) {
                float v = ex[h];
                for (int o2 = 32; o2; o2 >>= 1) v += __shfl_xor(v, o2);
                den[h] += v;
            }
        }
        float inv[4];
#pragma unroll
        for (int h = 0; h < 4; ++h) inv[h] = 1.f / den[h];
        for (int base = 0; base < deg; base += 64) {
            int e = base + lane;
            float w = 0.f;
            int cl = 0;
            if (e < deg) {
                cl = co[s0 + e];
                float4 sdv = *(const float4*)(sdst + (size_t)cl * 4);
                float sd[4] = {sdv.x, sdv.y, sdv.z, sdv.w};
#pragma unroll
                for (int h = 0; h < 4; ++h) {
                    float x = ss[h] + sd[h];
                    x = x > 0.f ? x : 0.01f * x;
                    w += __expf(x - mx[h]) * inv[h];
                }
            }
            int cnt2 = min(64, deg - base);
            for (int j = 0; j < cnt2; ++j) {
                float wj = __shfl(w, j);
                int   cj = __shfl(cl, j);
                unsigned int hv = *(const unsigned int*)(fbd + (size_t)cj * DOUT + lane * 2);
                acc0 = fmaf(wj, __uint_as_float(hv << 16), acc0);
                acc1 = fmaf(wj, __uint_as_float(hv & 0xffff0000u), acc1);
            }
        }
    }
    o[lane * 2]     = fmaxf(acc0, 0.f);
    o[lane * 2 + 1] = fmaxf(acc1, 0.f);
}

// ---------------- launch ----------------
extern "C" void kernel_launch(void* const* d_in, const int* in_sizes, int n_in,
                              void* d_out, int out_size, void* d_ws, size_t ws_size,
                              hipStream_t stream) {
    const float* u_prev  = (const float*)d_in[0];
    const float* i_prev  = (const float*)d_in[1];
    const float* w_user  = (const float*)d_in[2];
    const float* w_item  = (const float*)d_in[3];
    const float* a_u_src = (const float*)d_in[4];
    const float* a_u_dst = (const float*)d_in[5];
    const float* a_i_src = (const float*)d_in[6];
    const float* a_i_dst = (const float*)d_in[7];
    const int* u2i_row = (const int*)d_in[8];
    const int* u2i_col = (const int*)d_in[9];
    const int* i2u_row = (const int*)d_in[10];
    const int* i2u_col = (const int*)d_in[11];
    float* out = (float*)d_out;

    char* ws = (char*)d_ws;
    size_t woff = 0;
    auto alloc = [&](size_t bytes) -> char* {
        char* p = ws + woff;
        woff += (bytes + 255) & ~(size_t)255;
        return p;
    };
    unsigned short* AbigU = (unsigned short*)alloc((size_t)M_NODES * 512 * 2);
    unsigned short* AbigI = (unsigned short*)alloc((size_t)M_NODES * 512 * 2);
    unsigned short* BTu   = (unsigned short*)alloc((size_t)512 * 768 * 2);
    unsigned short* BTi   = (unsigned short*)alloc((size_t)512 * 768 * 2);
    unsigned short* fbu   = (unsigned short*)alloc((size_t)NC * M_NODES * DOUT * 2);
    unsigned short* fbi   = (unsigned short*)alloc((size_t)NC * M_NODES * DOUT * 2);
    float* cus    = (float*)alloc((size_t)NH * NC * DOUT * 4);
    float* cud    = (float*)alloc((size_t)NH * NC * DOUT * 4);
    float* cis    = (float*)alloc((size_t)NH * NC * DOUT * 4);
    float* cid    = (float*)alloc((size_t)NH * NC * DOUT * 4);
    float* su_src = (float*)alloc((size_t)NC * M_NODES * NH * 4);
    float* su_dst = (float*)alloc((size_t)NC * M_NODES * NH * 4);
    float* si_src = (float*)alloc((size_t)NC * M_NODES * NH * 4);
    float* si_dst = (float*)alloc((size_t)NC * M_NODES * NH * 4);
    int* csroff   = (int*)alloc((size_t)8 * (M_NODES + 1) * 4);
    int* csrcol   = (int*)alloc((size_t)8 * NE * 4);
    int* cnt3     = (int*)alloc((size_t)8 * NBKT * NBLK * 4);
    int* btot     = (int*)alloc((size_t)8 * NBKT * 4);
    int* bbase    = (int*)alloc((size_t)8 * NBKT * 4);
    unsigned int* pairbuf = (unsigned int*)alloc((size_t)8 * NE * 4);

    k_splitA<<<dim3((M_NODES * 32 + 255) / 256, 2), 256, 0, stream>>>(u_prev, i_prev, AbigU, AbigI);
    k_prepB<<<(DIN * DOUT + 255) / 256, 256, 0, stream>>>(w_user, w_item, BTu, BTi);
    k_cumsum_a<<<(NH * DOUT + 255) / 256, 256, 0, stream>>>(a_u_src, a_u_dst, a_i_src, a_i_dst,
                                                            cus, cud, cis, cid);
    dim3 ggrid((M_NODES + 127) / 128, NC);
    k_gmm<<<ggrid, 256, 0, stream>>>(AbigU, BTu, fbu);
    k_gmm<<<ggrid, 256, 0, stream>>>(AbigI, BTi, fbi);
    k_scores<<<(2 * M_NODES + 3) / 4, 256, 0, stream>>>(fbu, fbi, cus, cud, cis, cid,
                                                        su_src, su_dst, si_src, si_dst);
    k_bcount<<<dim3(NBLK, 8), 256, 0, stream>>>(u2i_row, i2u_row, cnt3);
    k_scanblocks<<<(8 * NBKT + 255) / 256, 256, 0, stream>>>(cnt3, btot);
    k_bbase<<<1, 512, 0, stream>>>(btot, bbase);
    k_bfill<<<dim3(NBLK, 8), 256, 0, stream>>>(u2i_row, u2i_col, i2u_row, i2u_col, cnt3, bbase, pairbuf);
    k_finalize<<<dim3(NBKT, 8), 256, 0, stream>>>(pairbuf, bbase, btot, csroff, csrcol);
    k_attend<<<dim3((M_NODES + 3) / 4, 8), 256, 0, stream>>>(fbu, fbi, su_src, su_dst,
                                                             si_src, si_dst, csroff, csrcol, out);
}

// Round 5
// 331.748 us; speedup vs baseline: 2.2822x; 1.1114x over previous
//
#include <hip/hip_runtime.h>
#include <math.h>

#define M_NODES 20000
#define MPAD    20096   // padded rows for tile-uniform staging
#define NE      320000
#define NC      4
#define NH      4
#define DIN     256
#define DOUT    128
#define DCAT    512   // NC * DOUT

// CSR bucket-build parameters
#define RPB   256
#define NBKT  79
#define EPB   2048
#define NBLK  157
#define CAP   8192

typedef __attribute__((ext_vector_type(8))) short short8v;
typedef __attribute__((ext_vector_type(4))) float f32x4;

__device__ __forceinline__ unsigned short f2bf(float x) {
    unsigned int u = __float_as_uint(x);
    unsigned int r = u + 0x7fffu + ((u >> 16) & 1u);
    return (unsigned short)(r >> 16);
}
__device__ __forceinline__ float bf2f(unsigned short h) {
    return __uint_as_float((unsigned int)h << 16);
}
__device__ __forceinline__ void gload16(const void* g, void* l) {
    __builtin_amdgcn_global_load_lds(
        (const __attribute__((address_space(1))) void*)g,
        (__attribute__((address_space(3))) void*)l,
        16, 0, 0);
}

// ---------------- A split: f32 (20000x256) -> [A_hi | A_lo] bf16 (20000x512) ----------------
__global__ __launch_bounds__(256) void k_splitA(const float* __restrict__ u_prev, const float* __restrict__ i_prev,
                                                unsigned short* __restrict__ AbigU, unsigned short* __restrict__ AbigI) {
    int t = blockIdx.x * 256 + threadIdx.x;
    if (t >= M_NODES * 32) return;
    int row = t >> 5, kc = (t & 31) * 8;
    const float* src = blockIdx.y ? i_prev : u_prev;
    unsigned short* dst = blockIdx.y ? AbigI : AbigU;
    float4 x0 = *(const float4*)(src + (size_t)row * DIN + kc);
    float4 x1 = *(const float4*)(src + (size_t)row * DIN + kc + 4);
    float xs[8] = {x0.x, x0.y, x0.z, x0.w, x1.x, x1.y, x1.z, x1.w};
    unsigned int H[4], L[4];
#pragma unroll
    for (int p = 0; p < 4; ++p) {
        unsigned short h0 = f2bf(xs[2 * p]);
        unsigned short h1 = f2bf(xs[2 * p + 1]);
        unsigned short l0 = f2bf(xs[2 * p] - bf2f(h0));
        unsigned short l1 = f2bf(xs[2 * p + 1] - bf2f(h1));
        H[p] = (unsigned int)h0 | ((unsigned int)h1 << 16);
        L[p] = (unsigned int)l0 | ((unsigned int)l1 << 16);
    }
    *(uint4*)(dst + (size_t)row * 512 + kc)       = make_uint4(H[0], H[1], H[2], H[3]);
    *(uint4*)(dst + (size_t)row * 512 + 256 + kc) = make_uint4(L[0], L[1], L[2], L[3]);
}

// ---------------- B prep: cumsum + split + transpose -> BT [512(n)][768(k)] bf16 ----------------
__global__ __launch_bounds__(256) void k_prepB(const float* __restrict__ w_user, const float* __restrict__ w_item,
                                               unsigned short* __restrict__ BTu, unsigned short* __restrict__ BTi) {
    int idx = blockIdx.x * 256 + threadIdx.x;
    if (idx >= DIN * DOUT) return;
    int k = idx >> 7, j = idx & 127;
    float su = 0.f, si = 0.f;
    for (int c = 0; c < NC; ++c) {
        su += w_user[((size_t)c * DIN + k) * DOUT + j];
        si += w_item[((size_t)c * DIN + k) * DOUT + j];
        size_t n = (size_t)(c * DOUT + j) * 768;
        unsigned short hu = f2bf(su), hi2 = f2bf(si);
        unsigned short lu = f2bf(su - bf2f(hu)), li = f2bf(si - bf2f(hi2));
        BTu[n + k] = hu;  BTu[n + 256 + k] = lu;  BTu[n + 512 + k] = hu;
        BTi[n + k] = hi2; BTi[n + 256 + k] = li;  BTi[n + 512 + k] = hi2;
    }
}

__global__ void k_cumsum_a(const float* __restrict__ aus, const float* __restrict__ aud,
                           const float* __restrict__ ais, const float* __restrict__ aid,
                           float* __restrict__ cus, float* __restrict__ cud,
                           float* __restrict__ cis, float* __restrict__ cid) {
    int idx = blockIdx.x * 256 + threadIdx.x;
    if (idx >= NH * DOUT) return;
    int h = idx / DOUT, d = idx % DOUT;
    float s0 = 0.f, s1 = 0.f, s2 = 0.f, s3 = 0.f;
    for (int c = 0; c < NC; ++c) {
        int o = (h * NC + c) * DOUT + d;
        s0 += aus[o]; s1 += aud[o]; s2 += ais[o]; s3 += aid[o];
        cus[o] = s0; cud[o] = s1; cis[o] = s2; cid[o] = s3;
    }
}

// ---------------- MFMA GEMM with global_load_lds staging ----------------
// grid (157, 4, 2); LDS [128][64] linear tiles; K = 768 (hi*hi, hi*lo, lo*hi)
__global__ __launch_bounds__(256) void k_gmm(const unsigned short* __restrict__ AbigU,
                                             const unsigned short* __restrict__ AbigI,
                                             const unsigned short* __restrict__ BTu,
                                             const unsigned short* __restrict__ BTi,
                                             unsigned short* __restrict__ fbu,
                                             unsigned short* __restrict__ fbi) {
    __shared__ unsigned short As[128 * 64];
    __shared__ unsigned short Bs[128 * 64];
    const unsigned short* Abig = blockIdx.z ? AbigI : AbigU;
    const unsigned short* BT   = blockIdx.z ? BTi  : BTu;
    unsigned short* fb         = blockIdx.z ? fbi  : fbu;
    int m0 = blockIdx.x * 128;
    int c  = blockIdx.y;
    int tid = threadIdx.x;
    int w = tid >> 6, lane = tid & 63;
    int wrb = (w >> 1) * 64, wcb = (w & 1) * 64;
    int l15 = lane & 15, g = lane >> 4;
    int srow = lane >> 3, scol = (lane & 7) * 8;     // staging: 8 rows x 64 cols per 1KB chunk
    f32x4 acc[4][4] = {};
    for (int kt = 0; kt < 12; ++kt) {
        int k0 = kt * 64;
        int acol0 = (k0 < 256) ? k0 : k0 - 256;      // k>=512 -> A_lo (cols 256-511)
#pragma unroll
        for (int t = 0; t < 4; ++t) {
            int chunk = w * 4 + t;
            int row8 = chunk * 8 + srow;
            gload16(Abig + (size_t)(m0 + row8) * 512 + acol0 + scol, (char*)As + chunk * 1024);
            gload16(BT + (size_t)(c * 128 + row8) * 768 + k0 + scol, (char*)Bs + chunk * 1024);
        }
        __syncthreads();
#pragma unroll
        for (int ks = 0; ks < 2; ++ks) {
            short8v a[4], b[4];
#pragma unroll
            for (int i = 0; i < 4; ++i)
                a[i] = *(const short8v*)(&As[(wrb + i * 16 + l15) * 64 + ks * 32 + g * 8]);
#pragma unroll
            for (int j = 0; j < 4; ++j)
                b[j] = *(const short8v*)(&Bs[(wcb + j * 16 + l15) * 64 + ks * 32 + g * 8]);
#pragma unroll
            for (int i = 0; i < 4; ++i)
#pragma unroll
                for (int j = 0; j < 4; ++j)
                    acc[i][j] = __builtin_amdgcn_mfma_f32_16x16x32_bf16(a[i], b[j], acc[i][j], 0, 0, 0);
        }
        __syncthreads();
    }
#pragma unroll
    for (int i = 0; i < 4; ++i) {
#pragma unroll
        for (int r = 0; r < 4; ++r) {
            int node = m0 + wrb + i * 16 + g * 4 + r;
            if (node < M_NODES) {
#pragma unroll
                for (int j = 0; j < 4; ++j) {
                    int d = wcb + j * 16 + l15;
                    fb[((size_t)c * M_NODES + node) * DOUT + d] = f2bf(acc[i][j][r]);
                }
            }
        }
    }
}

// ---------------- node attention scores (bf16 feature tables) ----------------
__global__ __launch_bounds__(256) void k_scores(const unsigned short* __restrict__ fbu, const unsigned short* __restrict__ fbi,
                                                const float* __restrict__ cus, const float* __restrict__ cud,
                                                const float* __restrict__ cis, const float* __restrict__ cid,
                                                float* __restrict__ su_src, float* __restrict__ su_dst,
                                                float* __restrict__ si_src, float* __restrict__ si_dst) {
    int wid  = (blockIdx.x * 256 + threadIdx.x) >> 6;
    int lane = threadIdx.x & 63;
    if (wid >= 2 * M_NODES) return;
    int side = wid >= M_NODES;
    int m = side ? wid - M_NODES : wid;
    const unsigned short* fb = side ? fbi : fbu;
    const float* Asrc = side ? cis : cus;
    const float* Adst = side ? cud : cid;
    float* Ssrc = side ? si_src : su_src;
    float* Sdst = side ? si_dst : su_dst;
    for (int c = 0; c < NC; ++c) {
        unsigned int hv = *(const unsigned int*)(fb + ((size_t)c * M_NODES + m) * DOUT + lane * 2);
        float v0 = __uint_as_float(hv << 16);
        float v1 = __uint_as_float(hv & 0xffff0000u);
        for (int hh = 0; hh < NH; ++hh) {
            int o = (hh * NC + c) * DOUT;
            float ps = v0 * Asrc[o + lane * 2] + v1 * Asrc[o + lane * 2 + 1];
            float pd = v0 * Adst[o + lane * 2] + v1 * Adst[o + lane * 2 + 1];
            for (int off = 32; off; off >>= 1) {
                ps += __shfl_xor(ps, off);
                pd += __shfl_xor(pd, off);
            }
            if (lane == 0) {
                Ssrc[(size_t)c * M_NODES * NH + m * NH + hh] = ps;
                Sdst[(size_t)c * M_NODES * NH + m * NH + hh] = pd;
            }
        }
    }
}

// ---------------- CSR build via coarse bucketing ----------------
__global__ __launch_bounds__(256) void k_bcount(const int* __restrict__ u2i_row, const int* __restrict__ i2u_row,
                                                int* __restrict__ cnt3) {
    __shared__ int hist[NBKT];
    int tid = threadIdx.x, blk = blockIdx.x, combo = blockIdx.y;
    int c = combo >> 1, dir = combo & 1;
    const int* rows = (dir ? i2u_row : u2i_row) + (size_t)c * NE;
    if (tid < NBKT) hist[tid] = 0;
    __syncthreads();
    int e0 = blk * EPB;
#pragma unroll
    for (int k = 0; k < 8; ++k) {
        int e = e0 + tid + k * 256;
        if (e < NE) atomicAdd(&hist[rows[e] >> 8], 1);
    }
    __syncthreads();
    if (tid < NBKT) cnt3[((size_t)combo * NBKT + tid) * NBLK + blk] = hist[tid];
}

__global__ void k_scanblocks(int* __restrict__ cnt3, int* __restrict__ btot) {
    int idx = blockIdx.x * 256 + threadIdx.x;
    if (idx >= 8 * NBKT) return;
    size_t base = (size_t)idx * NBLK;
    int run = 0;
    for (int b = 0; b < NBLK; ++b) {
        int v = cnt3[base + b];
        cnt3[base + b] = run;
        run += v;
    }
    btot[idx] = run;
}

__global__ __launch_bounds__(512) void k_bbase(const int* __restrict__ btot, int* __restrict__ bbase) {
    int wave = threadIdx.x >> 6, lane = threadIdx.x & 63;
    int carry = 0;
    for (int ch = 0; ch < 2; ++ch) {
        int idx = ch * 64 + lane;
        int v = (idx < NBKT) ? btot[wave * NBKT + idx] : 0;
        int inc = v;
        for (int off = 1; off < 64; off <<= 1) {
            int t = __shfl_up(inc, off);
            if (lane >= off) inc += t;
        }
        if (idx < NBKT) bbase[wave * NBKT + idx] = carry + inc - v;
        carry += __shfl(inc, 63);
    }
}

__global__ __launch_bounds__(256) void k_bfill(const int* __restrict__ u2i_row, const int* __restrict__ u2i_col,
                                               const int* __restrict__ i2u_row, const int* __restrict__ i2u_col,
                                               const int* __restrict__ cnt3, const int* __restrict__ bbase,
                                               unsigned int* __restrict__ pairbuf) {
    __shared__ int cur[NBKT];
    int tid = threadIdx.x, blk = blockIdx.x, combo = blockIdx.y;
    int c = combo >> 1, dir = combo & 1;
    const int* rows = (dir ? i2u_row : u2i_row) + (size_t)c * NE;
    const int* cols = (dir ? i2u_col : u2i_col) + (size_t)c * NE;
    if (tid < NBKT)
        cur[tid] = bbase[combo * NBKT + tid] + cnt3[((size_t)combo * NBKT + tid) * NBLK + blk];
    __syncthreads();
    unsigned int* pb = pairbuf + (size_t)combo * NE;
    int e0 = blk * EPB;
#pragma unroll
    for (int k = 0; k < 8; ++k) {
        int e = e0 + tid + k * 256;
        if (e < NE) {
            int r = rows[e], cl = cols[e];
            int pos = atomicAdd(&cur[r >> 8], 1);
            pb[pos] = ((unsigned int)r << 16) | (unsigned int)cl;
        }
    }
}

__global__ __launch_bounds__(256) void k_finalize(const unsigned int* __restrict__ pairbuf,
                                                  const int* __restrict__ bbase, const int* __restrict__ btot,
                                                  int* __restrict__ csroff, int* __restrict__ csrcol) {
    __shared__ int hist[RPB];
    __shared__ int cur[RPB];
    __shared__ int lcol[CAP];
    int tid = threadIdx.x, bkt = blockIdx.x, combo = blockIdx.y;
    int base = bbase[combo * NBKT + bkt];
    int cntb = btot[combo * NBKT + bkt];
    const unsigned int* pb = pairbuf + (size_t)combo * NE + base;
    int* ccol = csrcol + (size_t)combo * NE + base;
    hist[tid] = 0;
    __syncthreads();
    for (int k = tid; k < cntb; k += 256)
        atomicAdd(&hist[(pb[k] >> 16) & (RPB - 1)], 1);
    __syncthreads();
    for (int st = 1; st < RPB; st <<= 1) {
        int v = (tid >= st) ? hist[tid - st] : 0;
        __syncthreads();
        hist[tid] += v;
        __syncthreads();
    }
    int ex = (tid == 0) ? 0 : hist[tid - 1];
    cur[tid] = ex;
    int row = bkt * RPB + tid;
    if (row < M_NODES) csroff[combo * (M_NODES + 1) + row] = base + ex;
    if (bkt == NBKT - 1 && tid == 0) csroff[combo * (M_NODES + 1) + M_NODES] = NE;
    __syncthreads();
    for (int k = tid; k < cntb; k += 256) {
        unsigned int p = pb[k];
        int rl  = (p >> 16) & (RPB - 1);
        int col = (int)(p & 0xffffu);
        int pos = atomicAdd(&cur[rl], 1);
        if (pos < CAP) lcol[pos] = col; else ccol[pos] = col;
    }
    __syncthreads();
    int lim = min(cntb, CAP);
    for (int k = tid; k < lim; k += 256) ccol[k] = lcol[k];
}

// ---------------- attention: grid 40000 1-D, combo = bid&7 (XCD affinity) ----------------
__global__ __launch_bounds__(256) void k_attend(const unsigned short* __restrict__ fbu, const unsigned short* __restrict__ fbi,
                                                const float* __restrict__ su_src, const float* __restrict__ su_dst,
                                                const float* __restrict__ si_src, const float* __restrict__ si_dst,
                                                const int* __restrict__ off, const int* __restrict__ cols,
                                                float* __restrict__ out) {
    int bid = blockIdx.x;
    int combo = bid & 7, c = combo >> 1, dir = combo & 1;
    int wavein = threadIdx.x >> 6, lane = threadIdx.x & 63;
    int r = (bid >> 3) * 4 + wavein;
    const float* ssrc = (dir ? si_src : su_src) + (size_t)c * M_NODES * NH;
    const float* sdst = (dir ? su_dst : si_dst) + (size_t)c * M_NODES * NH;
    const unsigned short* fbd = (dir ? fbu : fbi) + (size_t)c * M_NODES * DOUT;
    float* o = out + ((size_t)(dir ? M_NODES + r : r)) * DCAT + c * DOUT;
    const int* co = cols + (size_t)combo * NE;
    int s0 = off[combo * (M_NODES + 1) + r];
    int s1 = off[combo * (M_NODES + 1) + r + 1];
    int deg = s1 - s0;

    if (deg <= 64) {
        float w = 0.f;
        int cl = 0;
        if (deg > 0) {
            float4 ssv = *(const float4*)(ssrc + (size_t)r * 4);
            float ss[4] = {ssv.x, ssv.y, ssv.z, ssv.w};
            float lg[4];
            if (lane < deg) {
                cl = co[s0 + lane];
                float4 sdv = *(const float4*)(sdst + (size_t)cl * 4);
                float sd[4] = {sdv.x, sdv.y, sdv.z, sdv.w};
#pragma unroll
                for (int h = 0; h < 4; ++h) {
                    float x = ss[h] + sd[h];
                    lg[h] = x > 0.f ? x : 0.01f * x;
                }
            } else {
#pragma unroll
                for (int h = 0; h < 4; ++h) lg[h] = -1e30f;
            }
            // no max pass: leaky_relu bounds logits (|x| <~ 40 << 88); clamp as a fuse
            float ex[4], den[4];
#pragma unroll
            for (int h = 0; h < 4; ++h) {
                ex[h] = __expf(fminf(lg[h], 80.f));
                den[h] = ex[h];
            }
#pragma unroll
            for (int h = 0; h < 4; ++h)
                for (int o2 = 32; o2; o2 >>= 1) den[h] += __shfl_xor(den[h], o2);
#pragma unroll
            for (int h = 0; h < 4; ++h) w += ex[h] * (1.f / den[h]);
        }
        // aggregation: 8 edges / iter (two independent uint4 gathers), 16 lanes x 8 bf16
        int q = lane >> 4, l16 = lane & 15;
        const unsigned short* fbl = fbd + l16 * 8;
        float a8[8] = {};
        int j = 0;
        for (; j + 8 <= deg; j += 8) {
            int e0 = j + q, e1 = j + 4 + q;
            float w0 = __shfl(w, e0), w1 = __shfl(w, e1);
            int   c0 = __shfl(cl, e0), c1 = __shfl(cl, e1);
            uint4 v0 = *(const uint4*)(fbl + (size_t)c0 * DOUT);
            uint4 v1 = *(const uint4*)(fbl + (size_t)c1 * DOUT);
            a8[0] = fmaf(w0, __uint_as_float(v0.x << 16), a8[0]);
            a8[1] = fmaf(w0, __uint_as_float(v0.x & 0xffff0000u), a8[1]);
            a8[2] = fmaf(w0, __uint_as_float(v0.y << 16), a8[2]);
            a8[3] = fmaf(w0, __uint_as_float(v0.y & 0xffff0000u), a8[3]);
            a8[4] = fmaf(w0, __uint_as_float(v0.z << 16), a8[4]);
            a8[5] = fmaf(w0, __uint_as_float(v0.z & 0xffff0000u), a8[5]);
            a8[6] = fmaf(w0, __uint_as_float(v0.w << 16), a8[6]);
            a8[7] = fmaf(w0, __uint_as_float(v0.w & 0xffff0000u), a8[7]);
            a8[0] = fmaf(w1, __uint_as_float(v1.x << 16), a8[0]);
            a8[1] = fmaf(w1, __uint_as_float(v1.x & 0xffff0000u), a8[1]);
            a8[2] = fmaf(w1, __uint_as_float(v1.y << 16), a8[2]);
            a8[3] = fmaf(w1, __uint_as_float(v1.y & 0xffff0000u), a8[3]);
            a8[4] = fmaf(w1, __uint_as_float(v1.z << 16), a8[4]);
            a8[5] = fmaf(w1, __uint_as_float(v1.z & 0xffff0000u), a8[5]);
            a8[6] = fmaf(w1, __uint_as_float(v1.w << 16), a8[6]);
            a8[7] = fmaf(w1, __uint_as_float(v1.w & 0xffff0000u), a8[7]);
        }
        for (; j < deg; j += 4) {
            int e = j + q;
            float we = __shfl(w, e & 63);
            int   ce = __shfl(cl, e & 63);
            if (e < deg) {
                uint4 v = *(const uint4*)(fbl + (size_t)ce * DOUT);
                a8[0] = fmaf(we, __uint_as_float(v.x << 16), a8[0]);
                a8[1] = fmaf(we, __uint_as_float(v.x & 0xffff0000u), a8[1]);
                a8[2] = fmaf(we, __uint_as_float(v.y << 16), a8[2]);
                a8[3] = fmaf(we, __uint_as_float(v.y & 0xffff0000u), a8[3]);
                a8[4] = fmaf(we, __uint_as_float(v.z << 16), a8[4]);
                a8[5] = fmaf(we, __uint_as_float(v.z & 0xffff0000u), a8[5]);
                a8[6] = fmaf(we, __uint_as_float(v.w << 16), a8[6]);
                a8[7] = fmaf(we, __uint_as_float(v.w & 0xffff0000u), a8[7]);
            }
        }
#pragma unroll
        for (int i = 0; i < 8; ++i) {
            a8[i] += __shfl_xor(a8[i], 16);
            a8[i] += __shfl_xor(a8[i], 32);
        }
        if (lane < 16) {
            float4 r0 = make_float4(fmaxf(a8[0], 0.f), fmaxf(a8[1], 0.f), fmaxf(a8[2], 0.f), fmaxf(a8[3], 0.f));
            float4 r1 = make_float4(fmaxf(a8[4], 0.f), fmaxf(a8[5], 0.f), fmaxf(a8[6], 0.f), fmaxf(a8[7], 0.f));
            *(float4*)(o + l16 * 8) = r0;
            *(float4*)(o + l16 * 8 + 4) = r1;
        }
        return;
    }

    // slow path (deg > 64): 2 passes (den, weight), no max pass
    float acc0 = 0.f, acc1 = 0.f;
    {
        float4 ssv = *(const float4*)(ssrc + (size_t)r * 4);
        float ss[4] = {ssv.x, ssv.y, ssv.z, ssv.w};
        float den[4] = {0.f, 0.f, 0.f, 0.f};
        for (int base = 0; base < deg; base += 64) {
            int e = base + lane;
            float ex[4] = {0.f, 0.f, 0.f, 0.f};
            if (e < deg) {
                int cl = co[s0 + e];
                float4 sdv = *(const float4*)(sdst + (size_t)cl * 4);
                float sd[4] = {sdv.x, sdv.y, sdv.z, sdv.w};
#pragma unroll
                for (int h = 0; h < 4; ++h) {
                    float x = ss[h] + sd[h];
                    x = x > 0.f ? x : 0.01f * x;
                    ex[h] = __expf(fminf(x, 80.f));
                }
            }
#pragma unroll
            for (int h = 0; h < 4; ++h) {
                float v = ex[h];
                for (int o2 = 32; o2; o2 >>= 1) v += __shfl_xor(v, o2);
                den[h] += v;
            }
        }
        float inv[4];
#pragma unroll
        for (int h = 0; h < 4; ++h) inv[h] = 1.f / den[h];
        for (int base = 0; base < deg; base += 64) {
            int e = base + lane;
            float w = 0.f;
            int cl = 0;
            if (e < deg) {
                cl = co[s0 + e];
                float4 sdv = *(const float4*)(sdst + (size_t)cl * 4);
                float sd[4] = {sdv.x, sdv.y, sdv.z, sdv.w};
#pragma unroll
                for (int h = 0; h < 4; ++h) {
                    float x = ss[h] + sd[h];
                    x = x > 0.f ? x : 0.01f * x;
                    w += __expf(fminf(x, 80.f)) * inv[h];
                }
            }
            int cnt2 = min(64, deg - base);
            for (int j = 0; j < cnt2; ++j) {
                float wj = __shfl(w, j);
                int   cj = __shfl(cl, j);
                unsigned int hv = *(const unsigned int*)(fbd + (size_t)cj * DOUT + lane * 2);
                acc0 = fmaf(wj, __uint_as_float(hv << 16), acc0);
                acc1 = fmaf(wj, __uint_as_float(hv & 0xffff0000u), acc1);
            }
        }
    }
    o[lane * 2]     = fmaxf(acc0, 0.f);
    o[lane * 2 + 1] = fmaxf(acc1, 0.f);
}

// ---------------- launch ----------------
extern "C" void kernel_launch(void* const* d_in, const int* in_sizes, int n_in,
                              void* d_out, int out_size, void* d_ws, size_t ws_size,
                              hipStream_t stream) {
    const float* u_prev  = (const float*)d_in[0];
    const float* i_prev  = (const float*)d_in[1];
    const float* w_user  = (const float*)d_in[2];
    const float* w_item  = (const float*)d_in[3];
    const float* a_u_src = (const float*)d_in[4];
    const float* a_u_dst = (const float*)d_in[5];
    const float* a_i_src = (const float*)d_in[6];
    const float* a_i_dst = (const float*)d_in[7];
    const int* u2i_row = (const int*)d_in[8];
    const int* u2i_col = (const int*)d_in[9];
    const int* i2u_row = (const int*)d_in[10];
    const int* i2u_col = (const int*)d_in[11];
    float* out = (float*)d_out;

    char* ws = (char*)d_ws;
    size_t woff = 0;
    auto alloc = [&](size_t bytes) -> char* {
        char* p = ws + woff;
        woff += (bytes + 255) & ~(size_t)255;
        return p;
    };
    unsigned short* AbigU = (unsigned short*)alloc((size_t)MPAD * 512 * 2);
    unsigned short* AbigI = (unsigned short*)alloc((size_t)MPAD * 512 * 2);
    unsigned short* BTu   = (unsigned short*)alloc((size_t)512 * 768 * 2);
    unsigned short* BTi   = (unsigned short*)alloc((size_t)512 * 768 * 2);
    unsigned short* fbu   = (unsigned short*)alloc((size_t)NC * M_NODES * DOUT * 2);
    unsigned short* fbi   = (unsigned short*)alloc((size_t)NC * M_NODES * DOUT * 2);
    float* cus    = (float*)alloc((size_t)NH * NC * DOUT * 4);
    float* cud    = (float*)alloc((size_t)NH * NC * DOUT * 4);
    float* cis    = (float*)alloc((size_t)NH * NC * DOUT * 4);
    float* cid    = (float*)alloc((size_t)NH * NC * DOUT * 4);
    float* su_src = (float*)alloc((size_t)NC * M_NODES * NH * 4);
    float* su_dst = (float*)alloc((size_t)NC * M_NODES * NH * 4);
    float* si_src = (float*)alloc((size_t)NC * M_NODES * NH * 4);
    float* si_dst = (float*)alloc((size_t)NC * M_NODES * NH * 4);
    int* csroff   = (int*)alloc((size_t)8 * (M_NODES + 1) * 4);
    int* csrcol   = (int*)alloc((size_t)8 * NE * 4);
    int* cnt3     = (int*)alloc((size_t)8 * NBKT * NBLK * 4);
    int* btot     = (int*)alloc((size_t)8 * NBKT * 4);
    int* bbase    = (int*)alloc((size_t)8 * NBKT * 4);
    unsigned int* pairbuf = (unsigned int*)alloc((size_t)8 * NE * 4);

    k_splitA<<<dim3((M_NODES * 32 + 255) / 256, 2), 256, 0, stream>>>(u_prev, i_prev, AbigU, AbigI);
    k_prepB<<<(DIN * DOUT + 255) / 256, 256, 0, stream>>>(w_user, w_item, BTu, BTi);
    k_cumsum_a<<<(NH * DOUT + 255) / 256, 256, 0, stream>>>(a_u_src, a_u_dst, a_i_src, a_i_dst,
                                                            cus, cud, cis, cid);
    k_gmm<<<dim3((M_NODES + 127) / 128, NC, 2), 256, 0, stream>>>(AbigU, AbigI, BTu, BTi, fbu, fbi);
    k_scores<<<(2 * M_NODES + 3) / 4, 256, 0, stream>>>(fbu, fbi, cus, cud, cis, cid,
                                                        su_src, su_dst, si_src, si_dst);
    k_bcount<<<dim3(NBLK, 8), 256, 0, stream>>>(u2i_row, i2u_row, cnt3);
    k_scanblocks<<<(8 * NBKT + 255) / 256, 256, 0, stream>>>(cnt3, btot);
    k_bbase<<<1, 512, 0, stream>>>(btot, bbase);
    k_bfill<<<dim3(NBLK, 8), 256, 0, stream>>>(u2i_row, u2i_col, i2u_row, i2u_col, cnt3, bbase, pairbuf);
    k_finalize<<<dim3(NBKT, 8), 256, 0, stream>>>(pairbuf, bbase, btot, csroff, csrcol);
    k_attend<<<dim3(M_NODES * 8 / 4), 256, 0, stream>>>(fbu, fbi, su_src, su_dst,
                                                        si_src, si_dst, csroff, csrcol, out);
}

// Round 6
// 217.700 us; speedup vs baseline: 3.4778x; 1.5239x over previous
//
#include <hip/hip_runtime.h>
#include <math.h>

#define M_NODES 20000
#define MPAD    20096   // padded rows for tile-uniform staging
#define NE      320000
#define NC      4
#define NH      4
#define DIN     256
#define DOUT    128
#define DCAT    512   // NC * DOUT

// CSR bucket-build parameters
#define RPB   256
#define NBKT  79
#define EPB   2048
#define NBLK  157
#define CAP   8192

typedef __attribute__((ext_vector_type(8))) short short8v;
typedef __attribute__((ext_vector_type(4))) float f32x4;

__device__ __forceinline__ unsigned short f2bf(float x) {
    unsigned int u = __float_as_uint(x);
    unsigned int r = u + 0x7fffu + ((u >> 16) & 1u);
    return (unsigned short)(r >> 16);
}
__device__ __forceinline__ float bf2f(unsigned short h) {
    return __uint_as_float((unsigned int)h << 16);
}
__device__ __forceinline__ void gload16(const void* g, void* l) {
    __builtin_amdgcn_global_load_lds(
        (const __attribute__((address_space(1))) void*)g,
        (__attribute__((address_space(3))) void*)l,
        16, 0, 0);
}

// ---------------- fused prep: splitA (u,i) | bcount | prepB | Bscore ----------------
// grid.x sections: [0,2500) splitA-u, [2500,5000) splitA-i, [5000,6256) bcount,
//                  [6256,6384) prepB, [6384,6400) Bscore
__global__ __launch_bounds__(256) void k_prep(const float* __restrict__ u_prev, const float* __restrict__ i_prev,
                                              const float* __restrict__ w_user, const float* __restrict__ w_item,
                                              const float* __restrict__ a_u_src, const float* __restrict__ a_u_dst,
                                              const float* __restrict__ a_i_src, const float* __restrict__ a_i_dst,
                                              const int* __restrict__ u2i_row, const int* __restrict__ i2u_row,
                                              unsigned short* __restrict__ AbigU, unsigned short* __restrict__ AbigI,
                                              unsigned short* __restrict__ BTu, unsigned short* __restrict__ BTi,
                                              unsigned short* __restrict__ Bscore, int* __restrict__ cnt3) {
    __shared__ int hist[NBKT];
    int bid = blockIdx.x, tid = threadIdx.x;
    if (bid < 5000) {
        // ---- splitA: f32 (20000x256) -> [A_hi | A_lo] bf16 (20000x512) ----
        int sideI = bid >= 2500;
        int t = (sideI ? bid - 2500 : bid) * 256 + tid;      // < 640000 exactly
        int row = t >> 5, kc = (t & 31) * 8;
        const float* src = sideI ? i_prev : u_prev;
        unsigned short* dst = sideI ? AbigI : AbigU;
        float4 x0 = *(const float4*)(src + (size_t)row * DIN + kc);
        float4 x1 = *(const float4*)(src + (size_t)row * DIN + kc + 4);
        float xs[8] = {x0.x, x0.y, x0.z, x0.w, x1.x, x1.y, x1.z, x1.w};
        unsigned int H[4], L[4];
#pragma unroll
        for (int p = 0; p < 4; ++p) {
            unsigned short h0 = f2bf(xs[2 * p]);
            unsigned short h1 = f2bf(xs[2 * p + 1]);
            unsigned short l0 = f2bf(xs[2 * p] - bf2f(h0));
            unsigned short l1 = f2bf(xs[2 * p + 1] - bf2f(h1));
            H[p] = (unsigned int)h0 | ((unsigned int)h1 << 16);
            L[p] = (unsigned int)l0 | ((unsigned int)l1 << 16);
        }
        *(uint4*)(dst + (size_t)row * 512 + kc)       = make_uint4(H[0], H[1], H[2], H[3]);
        *(uint4*)(dst + (size_t)row * 512 + 256 + kc) = make_uint4(L[0], L[1], L[2], L[3]);
        return;
    }
    if (bid < 6256) {
        // ---- bcount ----
        int sub = bid - 5000;
        int combo = sub / NBLK, blk = sub % NBLK;
        int c = combo >> 1, dir = combo & 1;
        const int* rows = (dir ? i2u_row : u2i_row) + (size_t)c * NE;
        if (tid < NBKT) hist[tid] = 0;
        __syncthreads();
        int e0 = blk * EPB;
#pragma unroll
        for (int k = 0; k < 8; ++k) {
            int e = e0 + tid + k * 256;
            if (e < NE) atomicAdd(&hist[rows[e] >> 8], 1);
        }
        __syncthreads();
        if (tid < NBKT) cnt3[((size_t)combo * NBKT + tid) * NBLK + blk] = hist[tid];
        return;
    }
    if (bid < 6384) {
        // ---- prepB: cumsum + split + transpose -> BT [512(n)][768(k)] ----
        int idx = (bid - 6256) * 256 + tid;                  // < 32768 exactly
        int k = idx >> 7, j = idx & 127;
        float su = 0.f, si = 0.f;
        for (int c = 0; c < NC; ++c) {
            su += w_user[((size_t)c * DIN + k) * DOUT + j];
            si += w_item[((size_t)c * DIN + k) * DOUT + j];
            size_t n = (size_t)(c * DOUT + j) * 768;
            unsigned short hu = f2bf(su), hi2 = f2bf(si);
            unsigned short lu = f2bf(su - bf2f(hu)), li = f2bf(si - bf2f(hi2));
            BTu[n + k] = hu;  BTu[n + 256 + k] = lu;  BTu[n + 512 + k] = hu;
            BTi[n + k] = hi2; BTi[n + 256 + k] = li;  BTi[n + 512 + k] = hi2;
        }
        return;
    }
    {
        // ---- Bscore: fragment-major block-diagonal attention matrix ----
        // layout [side][ntile][kstep][lane][8]; value(k = kstep*32+(lane>>4)*8+j, col = ntile*16+(lane&15))
        int t = (bid - 6384) * 256 + tid;                    // < 4096 exactly
        int side = t >> 11, nt = (t >> 10) & 1, kstep = (t >> 6) & 15, ln = t & 63;
        int g = ln >> 4, l15 = ln & 15;
        int cc = nt * 2 + (l15 >> 3), kind = (l15 >> 2) & 1, h = l15 & 3;
        const float* araw = kind ? (side ? a_u_dst : a_i_dst) : (side ? a_i_src : a_u_src);
        unsigned int out2[4];
#pragma unroll
        for (int p = 0; p < 4; ++p) {
            unsigned short e2[2];
#pragma unroll
            for (int q = 0; q < 2; ++q) {
                int j = p * 2 + q;
                int k = kstep * 32 + g * 8 + j;
                int kc = k >> 7, d = k & 127;
                float s = 0.f;
                if (kc == cc)
                    for (int c2 = 0; c2 <= cc; ++c2) s += araw[(h * NC + c2) * DOUT + d];
                e2[q] = f2bf(s);
            }
            out2[p] = (unsigned int)e2[0] | ((unsigned int)e2[1] << 16);
        }
        *(uint4*)(Bscore + ((size_t)(((side * 2 + nt) * 16 + kstep) * 64 + ln)) * 8) =
            make_uint4(out2[0], out2[1], out2[2], out2[3]);
    }
}

// ---------------- MFMA GEMM with global_load_lds staging (unchanged) ----------------
__global__ __launch_bounds__(256) void k_gmm(const unsigned short* __restrict__ AbigU,
                                             const unsigned short* __restrict__ AbigI,
                                             const unsigned short* __restrict__ BTu,
                                             const unsigned short* __restrict__ BTi,
                                             unsigned short* __restrict__ fbu,
                                             unsigned short* __restrict__ fbi) {
    __shared__ unsigned short As[128 * 64];
    __shared__ unsigned short Bs[128 * 64];
    const unsigned short* Abig = blockIdx.z ? AbigI : AbigU;
    const unsigned short* BT   = blockIdx.z ? BTi  : BTu;
    unsigned short* fb         = blockIdx.z ? fbi  : fbu;
    int m0 = blockIdx.x * 128;
    int c  = blockIdx.y;
    int tid = threadIdx.x;
    int w = tid >> 6, lane = tid & 63;
    int wrb = (w >> 1) * 64, wcb = (w & 1) * 64;
    int l15 = lane & 15, g = lane >> 4;
    int srow = lane >> 3, scol = (lane & 7) * 8;
    f32x4 acc[4][4] = {};
    for (int kt = 0; kt < 12; ++kt) {
        int k0 = kt * 64;
        int acol0 = (k0 < 256) ? k0 : k0 - 256;
#pragma unroll
        for (int t = 0; t < 4; ++t) {
            int chunk = w * 4 + t;
            int row8 = chunk * 8 + srow;
            gload16(Abig + (size_t)(m0 + row8) * 512 + acol0 + scol, (char*)As + chunk * 1024);
            gload16(BT + (size_t)(c * 128 + row8) * 768 + k0 + scol, (char*)Bs + chunk * 1024);
        }
        __syncthreads();
#pragma unroll
        for (int ks = 0; ks < 2; ++ks) {
            short8v a[4], b[4];
#pragma unroll
            for (int i = 0; i < 4; ++i)
                a[i] = *(const short8v*)(&As[(wrb + i * 16 + l15) * 64 + ks * 32 + g * 8]);
#pragma unroll
            for (int j = 0; j < 4; ++j)
                b[j] = *(const short8v*)(&Bs[(wcb + j * 16 + l15) * 64 + ks * 32 + g * 8]);
#pragma unroll
            for (int i = 0; i < 4; ++i)
#pragma unroll
                for (int j = 0; j < 4; ++j)
                    acc[i][j] = __builtin_amdgcn_mfma_f32_16x16x32_bf16(a[i], b[j], acc[i][j], 0, 0, 0);
        }
        __syncthreads();
    }
#pragma unroll
    for (int i = 0; i < 4; ++i) {
#pragma unroll
        for (int r = 0; r < 4; ++r) {
            int node = m0 + wrb + i * 16 + g * 4 + r;
            if (node < M_NODES) {
#pragma unroll
                for (int j = 0; j < 4; ++j) {
                    int d = wcb + j * 16 + l15;
                    fb[((size_t)c * M_NODES + node) * DOUT + d] = f2bf(acc[i][j][r]);
                }
            }
        }
    }
}

// ---------------- scores via MFMA: (nodes x 512 fb) @ (512 x 32 block-diag Bscore) ----------------
__global__ __launch_bounds__(256) void k_scoresMM(const unsigned short* __restrict__ fbu,
                                                  const unsigned short* __restrict__ fbi,
                                                  const unsigned short* __restrict__ Bscore,
                                                  float* __restrict__ su_src, float* __restrict__ su_dst,
                                                  float* __restrict__ si_src, float* __restrict__ si_dst) {
    int side = blockIdx.y;
    const unsigned short* fb = side ? fbi : fbu;
    int wv = threadIdx.x >> 6, lane = threadIdx.x & 63;
    int nb = (blockIdx.x * 4 + wv) * 16;
    int l15 = lane & 15, g = lane >> 4;
    int node = nb + l15;
    int nload = node < M_NODES ? node : 0;
    f32x4 acc0 = {}, acc1 = {};
    const unsigned short* bs = Bscore + (size_t)side * 2 * 16 * 64 * 8;
    for (int ks = 0; ks < 16; ++ks) {
        int cch = ks >> 2;
        int off = (ks & 3) * 32 + g * 8;
        short8v a  = *(const short8v*)(fb + ((size_t)cch * M_NODES + nload) * DOUT + off);
        short8v b0 = *(const short8v*)(bs + ((size_t)(ks) * 64 + lane) * 8);
        short8v b1 = *(const short8v*)(bs + ((size_t)(16 + ks) * 64 + lane) * 8);
        acc0 = __builtin_amdgcn_mfma_f32_16x16x32_bf16(a, b0, acc0, 0, 0, 0);
        acc1 = __builtin_amdgcn_mfma_f32_16x16x32_bf16(a, b1, acc1, 0, 0, 0);
    }
    int kind = (l15 >> 2) & 1, h = l15 & 3;
    float* dst = kind ? (side ? si_dst : su_dst) : (side ? si_src : su_src);
#pragma unroll
    for (int nt = 0; nt < 2; ++nt) {
        int cc = nt * 2 + (l15 >> 3);
        f32x4 acc = nt ? acc1 : acc0;
#pragma unroll
        for (int rr = 0; rr < 4; ++rr) {
            int nrow = nb + g * 4 + rr;
            if (nrow < M_NODES)
                dst[((size_t)cc * M_NODES + nrow) * 4 + h] = acc[rr];
        }
    }
}

// ---------------- fused scan: per-(combo,bucket) block scan + bucket bases ----------------
__global__ __launch_bounds__(256) void k_scan2(int* __restrict__ cnt3, int* __restrict__ btot,
                                               int* __restrict__ bbase) {
    __shared__ int tot[128];
    int combo = blockIdx.x, tid = threadIdx.x;
    if (tid < NBKT) {
        size_t base = ((size_t)combo * NBKT + tid) * NBLK;
        int run = 0;
        for (int b = 0; b < NBLK; ++b) {
            int v = cnt3[base + b];
            cnt3[base + b] = run;
            run += v;
        }
        tot[tid] = run;
        btot[combo * NBKT + tid] = run;
    }
    __syncthreads();
    if (tid < 64) {
        int carry = 0;
        for (int ch = 0; ch < 2; ++ch) {
            int idx = ch * 64 + tid;
            int v = (idx < NBKT) ? tot[idx] : 0;
            int inc = v;
            for (int o = 1; o < 64; o <<= 1) {
                int tv = __shfl_up(inc, o);
                if (tid >= o) inc += tv;
            }
            if (idx < NBKT) bbase[combo * NBKT + idx] = carry + inc - v;
            carry += __shfl(inc, 63);
        }
    }
}

__global__ __launch_bounds__(256) void k_bfill(const int* __restrict__ u2i_row, const int* __restrict__ u2i_col,
                                               const int* __restrict__ i2u_row, const int* __restrict__ i2u_col,
                                               const int* __restrict__ cnt3, const int* __restrict__ bbase,
                                               unsigned int* __restrict__ pairbuf) {
    __shared__ int cur[NBKT];
    int tid = threadIdx.x, blk = blockIdx.x, combo = blockIdx.y;
    int c = combo >> 1, dir = combo & 1;
    const int* rows = (dir ? i2u_row : u2i_row) + (size_t)c * NE;
    const int* cols = (dir ? i2u_col : u2i_col) + (size_t)c * NE;
    if (tid < NBKT)
        cur[tid] = bbase[combo * NBKT + tid] + cnt3[((size_t)combo * NBKT + tid) * NBLK + blk];
    __syncthreads();
    unsigned int* pb = pairbuf + (size_t)combo * NE;
    int e0 = blk * EPB;
#pragma unroll
    for (int k = 0; k < 8; ++k) {
        int e = e0 + tid + k * 256;
        if (e < NE) {
            int r = rows[e], cl = cols[e];
            int pos = atomicAdd(&cur[r >> 8], 1);
            pb[pos] = ((unsigned int)r << 16) | (unsigned int)cl;
        }
    }
}

__global__ __launch_bounds__(256) void k_finalize(const unsigned int* __restrict__ pairbuf,
                                                  const int* __restrict__ bbase, const int* __restrict__ btot,
                                                  int* __restrict__ csroff, int* __restrict__ csrcol) {
    __shared__ int hist[RPB];
    __shared__ int cur[RPB];
    __shared__ int lcol[CAP];
    int tid = threadIdx.x, bkt = blockIdx.x, combo = blockIdx.y;
    int base = bbase[combo * NBKT + bkt];
    int cntb = btot[combo * NBKT + bkt];
    const unsigned int* pb = pairbuf + (size_t)combo * NE + base;
    int* ccol = csrcol + (size_t)combo * NE + base;
    hist[tid] = 0;
    __syncthreads();
    for (int k = tid; k < cntb; k += 256)
        atomicAdd(&hist[(pb[k] >> 16) & (RPB - 1)], 1);
    __syncthreads();
    for (int st = 1; st < RPB; st <<= 1) {
        int v = (tid >= st) ? hist[tid - st] : 0;
        __syncthreads();
        hist[tid] += v;
        __syncthreads();
    }
    int ex = (tid == 0) ? 0 : hist[tid - 1];
    cur[tid] = ex;
    int row = bkt * RPB + tid;
    if (row < M_NODES) csroff[combo * (M_NODES + 1) + row] = base + ex;
    if (bkt == NBKT - 1 && tid == 0) csroff[combo * (M_NODES + 1) + M_NODES] = NE;
    __syncthreads();
    for (int k = tid; k < cntb; k += 256) {
        unsigned int p = pb[k];
        int rl  = (p >> 16) & (RPB - 1);
        int col = (int)(p & 0xffffu);
        int pos = atomicAdd(&cur[rl], 1);
        if (pos < CAP) lcol[pos] = col; else ccol[pos] = col;
    }
    __syncthreads();
    int lim = min(cntb, CAP);
    for (int k = tid; k < lim; k += 256) ccol[k] = lcol[k];
}

// ---------------- full-wave fallback for one row (deg up to 64 fast; >64 slow) ----------------
__device__ void attend_row_wave(int r, int s0, int deg, const float* __restrict__ ssrc,
                                const float* __restrict__ sdst, const unsigned short* __restrict__ fbd,
                                const int* __restrict__ co, float* __restrict__ o, int lane) {
    if (deg <= 64) {
        float w = 0.f;
        int cl = 0;
        if (deg > 0) {
            float4 ssv = *(const float4*)(ssrc + (size_t)r * 4);
            float ss[4] = {ssv.x, ssv.y, ssv.z, ssv.w};
            float lg[4];
            if (lane < deg) {
                cl = co[s0 + lane];
                float4 sdv = *(const float4*)(sdst + (size_t)cl * 4);
                float sd[4] = {sdv.x, sdv.y, sdv.z, sdv.w};
#pragma unroll
                for (int h = 0; h < 4; ++h) {
                    float x = ss[h] + sd[h];
                    lg[h] = x > 0.f ? x : 0.01f * x;
                }
            } else {
#pragma unroll
                for (int h = 0; h < 4; ++h) lg[h] = -1e30f;
            }
            float ex[4], den[4];
#pragma unroll
            for (int h = 0; h < 4; ++h) {
                ex[h] = __expf(fminf(lg[h], 80.f));
                den[h] = ex[h];
            }
#pragma unroll
            for (int h = 0; h < 4; ++h)
                for (int o2 = 32; o2; o2 >>= 1) den[h] += __shfl_xor(den[h], o2);
#pragma unroll
            for (int h = 0; h < 4; ++h) w += ex[h] * (1.f / den[h]);
        }
        int q = lane >> 4, l16 = lane & 15;
        const unsigned short* fbl = fbd + l16 * 8;
        float a8[8] = {};
        for (int j = 0; j < deg; j += 4) {
            int e = j + q;
            float we = __shfl(w, e & 63);
            int   ce = __shfl(cl, e & 63);
            if (e < deg) {
                uint4 v = *(const uint4*)(fbl + (size_t)ce * DOUT);
                a8[0] = fmaf(we, __uint_as_float(v.x << 16), a8[0]);
                a8[1] = fmaf(we, __uint_as_float(v.x & 0xffff0000u), a8[1]);
                a8[2] = fmaf(we, __uint_as_float(v.y << 16), a8[2]);
                a8[3] = fmaf(we, __uint_as_float(v.y & 0xffff0000u), a8[3]);
                a8[4] = fmaf(we, __uint_as_float(v.z << 16), a8[4]);
                a8[5] = fmaf(we, __uint_as_float(v.z & 0xffff0000u), a8[5]);
                a8[6] = fmaf(we, __uint_as_float(v.w << 16), a8[6]);
                a8[7] = fmaf(we, __uint_as_float(v.w & 0xffff0000u), a8[7]);
            }
        }
#pragma unroll
        for (int i = 0; i < 8; ++i) {
            a8[i] += __shfl_xor(a8[i], 16);
            a8[i] += __shfl_xor(a8[i], 32);
        }
        if (lane < 16) {
            float4 r0 = make_float4(fmaxf(a8[0], 0.f), fmaxf(a8[1], 0.f), fmaxf(a8[2], 0.f), fmaxf(a8[3], 0.f));
            float4 r1 = make_float4(fmaxf(a8[4], 0.f), fmaxf(a8[5], 0.f), fmaxf(a8[6], 0.f), fmaxf(a8[7], 0.f));
            *(float4*)(o + l16 * 8) = r0;
            *(float4*)(o + l16 * 8 + 4) = r1;
        }
        return;
    }
    // slow path (deg > 64)
    float acc0 = 0.f, acc1 = 0.f;
    {
        float4 ssv = *(const float4*)(ssrc + (size_t)r * 4);
        float ss[4] = {ssv.x, ssv.y, ssv.z, ssv.w};
        float den[4] = {0.f, 0.f, 0.f, 0.f};
        for (int base = 0; base < deg; base += 64) {
            int e = base + lane;
            float ex[4] = {0.f, 0.f, 0.f, 0.f};
            if (e < deg) {
                int cl = co[s0 + e];
                float4 sdv = *(const float4*)(sdst + (size_t)cl * 4);
                float sd[4] = {sdv.x, sdv.y, sdv.z, sdv.w};
#pragma unroll
                for (int h = 0; h < 4; ++h) {
                    float x = ss[h] + sd[h];
                    x = x > 0.f ? x : 0.01f * x;
                    ex[h] = __expf(fminf(x, 80.f));
                }
            }
#pragma unroll
            for (int h = 0; h < 4; ++h) {
                float v = ex[h];
                for (int o2 = 32; o2; o2 >>= 1) v += __shfl_xor(v, o2);
                den[h] += v;
            }
        }
        float inv[4];
#pragma unroll
        for (int h = 0; h < 4; ++h) inv[h] = 1.f / den[h];
        for (int base = 0; base < deg; base += 64) {
            int e = base + lane;
            float w = 0.f;
            int cl = 0;
            if (e < deg) {
                cl = co[s0 + e];
                float4 sdv = *(const float4*)(sdst + (size_t)cl * 4);
                float sd[4] = {sdv.x, sdv.y, sdv.z, sdv.w};
#pragma unroll
                for (int h = 0; h < 4; ++h) {
                    float x = ss[h] + sd[h];
                    x = x > 0.f ? x : 0.01f * x;
                    w += __expf(fminf(x, 80.f)) * inv[h];
                }
            }
            int cnt2 = min(64, deg - base);
            for (int j = 0; j < cnt2; ++j) {
                float wj = __shfl(w, j);
                int   cj = __shfl(cl, j);
                unsigned int hv = *(const unsigned int*)(fbd + (size_t)cj * DOUT + lane * 2);
                acc0 = fmaf(wj, __uint_as_float(hv << 16), acc0);
                acc1 = fmaf(wj, __uint_as_float(hv & 0xffff0000u), acc1);
            }
        }
    }
    o[lane * 2]     = fmaxf(acc0, 0.f);
    o[lane * 2 + 1] = fmaxf(acc1, 0.f);
}

// ---------------- attention: 2 rows per wave (32-lane halves), combo = bid&7 ----------------
__global__ __launch_bounds__(256) void k_attend(const unsigned short* __restrict__ fbu, const unsigned short* __restrict__ fbi,
                                                const float* __restrict__ su_src, const float* __restrict__ su_dst,
                                                const float* __restrict__ si_src, const float* __restrict__ si_dst,
                                                const int* __restrict__ off, const int* __restrict__ cols,
                                                float* __restrict__ out) {
    int bid = blockIdx.x;
    int combo = bid & 7, c = combo >> 1, dir = combo & 1;
    int wavein = threadIdx.x >> 6, lane = threadIdx.x & 63;
    int half = lane >> 5, l = lane & 31;
    int rbase = (bid >> 3) * 8 + wavein * 2;
    const float* ssrc = (dir ? si_src : su_src) + (size_t)c * M_NODES * NH;
    const float* sdst = (dir ? su_dst : si_dst) + (size_t)c * M_NODES * NH;
    const unsigned short* fbd = (dir ? fbu : fbi) + (size_t)c * M_NODES * DOUT;
    const int* co = cols + (size_t)combo * NE;
    const int* offc = off + combo * (M_NODES + 1);
    int r = rbase + half;
    int s0 = offc[r];
    int deg = offc[r + 1] - s0;
    int degmax = max(deg, __shfl_xor(deg, 32));
    float* o = out + ((size_t)(dir ? M_NODES + r : r)) * DCAT + c * DOUT;

    if (degmax <= 32) {
        // -------- half-path: each 32-lane half owns one row --------
        float w = 0.f;
        int cl = 0;
        if (deg > 0) {
            float4 ssv = *(const float4*)(ssrc + (size_t)r * 4);
            float ss[4] = {ssv.x, ssv.y, ssv.z, ssv.w};
            float lg[4];
            if (l < deg) {
                cl = co[s0 + l];
                float4 sdv = *(const float4*)(sdst + (size_t)cl * 4);
                float sd[4] = {sdv.x, sdv.y, sdv.z, sdv.w};
#pragma unroll
                for (int h = 0; h < 4; ++h) {
                    float x = ss[h] + sd[h];
                    lg[h] = x > 0.f ? x : 0.01f * x;
                }
            } else {
#pragma unroll
                for (int h = 0; h < 4; ++h) lg[h] = -1e30f;
            }
            float ex[4], den[4];
#pragma unroll
            for (int h = 0; h < 4; ++h) {
                ex[h] = __expf(fminf(lg[h], 80.f));
                den[h] = ex[h];
            }
#pragma unroll
            for (int h = 0; h < 4; ++h)
                for (int o2 = 16; o2; o2 >>= 1) den[h] += __shfl_xor(den[h], o2);
#pragma unroll
            for (int h = 0; h < 4; ++h) w += ex[h] * (1.f / den[h]);
        }
        // aggregation: per half 4 edges/iter (2 slots x 2 unroll), 16 lanes x 8 bf16
        int q2 = (l >> 4), l16 = l & 15;
        const unsigned short* fbl = fbd + l16 * 8;
        float a8[8] = {};
        int hb = half * 32;
        for (int j = 0; j < deg; j += 4) {
            int e0 = j + q2, e1 = j + 2 + q2;
            float w0 = __shfl(w, hb + min(e0, 31));
            float w1 = __shfl(w, hb + min(e1, 31));
            int   c0 = __shfl(cl, hb + min(e0, 31));
            int   c1 = __shfl(cl, hb + min(e1, 31));
            w0 = (e0 < deg) ? w0 : 0.f;
            w1 = (e1 < deg) ? w1 : 0.f;
            uint4 v0 = *(const uint4*)(fbl + (size_t)c0 * DOUT);
            uint4 v1 = *(const uint4*)(fbl + (size_t)c1 * DOUT);
            a8[0] = fmaf(w0, __uint_as_float(v0.x << 16), a8[0]);
            a8[1] = fmaf(w0, __uint_as_float(v0.x & 0xffff0000u), a8[1]);
            a8[2] = fmaf(w0, __uint_as_float(v0.y << 16), a8[2]);
            a8[3] = fmaf(w0, __uint_as_float(v0.y & 0xffff0000u), a8[3]);
            a8[4] = fmaf(w0, __uint_as_float(v0.z << 16), a8[4]);
            a8[5] = fmaf(w0, __uint_as_float(v0.z & 0xffff0000u), a8[5]);
            a8[6] = fmaf(w0, __uint_as_float(v0.w << 16), a8[6]);
            a8[7] = fmaf(w0, __uint_as_float(v0.w & 0xffff0000u), a8[7]);
            a8[0] = fmaf(w1, __uint_as_float(v1.x << 16), a8[0]);
            a8[1] = fmaf(w1, __uint_as_float(v1.x & 0xffff0000u), a8[1]);
            a8[2] = fmaf(w1, __uint_as_float(v1.y << 16), a8[2]);
            a8[3] = fmaf(w1, __uint_as_float(v1.y & 0xffff0000u), a8[3]);
            a8[4] = fmaf(w1, __uint_as_float(v1.z << 16), a8[4]);
            a8[5] = fmaf(w1, __uint_as_float(v1.z & 0xffff0000u), a8[5]);
            a8[6] = fmaf(w1, __uint_as_float(v1.w << 16), a8[6]);
            a8[7] = fmaf(w1, __uint_as_float(v1.w & 0xffff0000u), a8[7]);
        }
#pragma unroll
        for (int i = 0; i < 8; ++i) a8[i] += __shfl_xor(a8[i], 16);
        if (l < 16) {
            float4 r0 = make_float4(fmaxf(a8[0], 0.f), fmaxf(a8[1], 0.f), fmaxf(a8[2], 0.f), fmaxf(a8[3], 0.f));
            float4 r1 = make_float4(fmaxf(a8[4], 0.f), fmaxf(a8[5], 0.f), fmaxf(a8[6], 0.f), fmaxf(a8[7], 0.f));
            *(float4*)(o + l16 * 8) = r0;
            *(float4*)(o + l16 * 8 + 4) = r1;
        }
        return;
    }

    // -------- rare fallback: process the two rows sequentially with the full wave --------
    for (int rr = 0; rr < 2; ++rr) {
        int r2 = rbase + rr;
        int t0 = offc[r2];
        int d2 = offc[r2 + 1] - t0;
        float* o2 = out + ((size_t)(dir ? M_NODES + r2 : r2)) * DCAT + c * DOUT;
        attend_row_wave(r2, t0, d2, ssrc, sdst, fbd, co, o2, lane);
    }
}

// ---------------- launch ----------------
extern "C" void kernel_launch(void* const* d_in, const int* in_sizes, int n_in,
                              void* d_out, int out_size, void* d_ws, size_t ws_size,
                              hipStream_t stream) {
    const float* u_prev  = (const float*)d_in[0];
    const float* i_prev  = (const float*)d_in[1];
    const float* w_user  = (const float*)d_in[2];
    const float* w_item  = (const float*)d_in[3];
    const float* a_u_src = (const float*)d_in[4];
    const float* a_u_dst = (const float*)d_in[5];
    const float* a_i_src = (const float*)d_in[6];
    const float* a_i_dst = (const float*)d_in[7];
    const int* u2i_row = (const int*)d_in[8];
    const int* u2i_col = (const int*)d_in[9];
    const int* i2u_row = (const int*)d_in[10];
    const int* i2u_col = (const int*)d_in[11];
    float* out = (float*)d_out;

    char* ws = (char*)d_ws;
    size_t woff = 0;
    auto alloc = [&](size_t bytes) -> char* {
        char* p = ws + woff;
        woff += (bytes + 255) & ~(size_t)255;
        return p;
    };
    unsigned short* AbigU = (unsigned short*)alloc((size_t)MPAD * 512 * 2);
    unsigned short* AbigI = (unsigned short*)alloc((size_t)MPAD * 512 * 2);
    unsigned short* BTu   = (unsigned short*)alloc((size_t)512 * 768 * 2);
    unsigned short* BTi   = (unsigned short*)alloc((size_t)512 * 768 * 2);
    unsigned short* Bscore= (unsigned short*)alloc((size_t)2 * 2 * 16 * 64 * 8 * 2);
    unsigned short* fbu   = (unsigned short*)alloc((size_t)NC * M_NODES * DOUT * 2);
    unsigned short* fbi   = (unsigned short*)alloc((size_t)NC * M_NODES * DOUT * 2);
    float* su_src = (float*)alloc((size_t)NC * M_NODES * NH * 4);
    float* su_dst = (float*)alloc((size_t)NC * M_NODES * NH * 4);
    float* si_src = (float*)alloc((size_t)NC * M_NODES * NH * 4);
    float* si_dst = (float*)alloc((size_t)NC * M_NODES * NH * 4);
    int* csroff   = (int*)alloc((size_t)8 * (M_NODES + 1) * 4);
    int* csrcol   = (int*)alloc((size_t)8 * NE * 4);
    int* cnt3     = (int*)alloc((size_t)8 * NBKT * NBLK * 4);
    int* btot     = (int*)alloc((size_t)8 * NBKT * 4);
    int* bbase    = (int*)alloc((size_t)8 * NBKT * 4);
    unsigned int* pairbuf = (unsigned int*)alloc((size_t)8 * NE * 4);

    k_prep<<<6400, 256, 0, stream>>>(u_prev, i_prev, w_user, w_item,
                                     a_u_src, a_u_dst, a_i_src, a_i_dst,
                                     u2i_row, i2u_row,
                                     AbigU, AbigI, BTu, BTi, Bscore, cnt3);
    k_gmm<<<dim3((M_NODES + 127) / 128, NC, 2), 256, 0, stream>>>(AbigU, AbigI, BTu, BTi, fbu, fbi);
    k_scoresMM<<<dim3((M_NODES + 63) / 64, 2), 256, 0, stream>>>(fbu, fbi, Bscore,
                                                                 su_src, su_dst, si_src, si_dst);
    k_scan2<<<8, 256, 0, stream>>>(cnt3, btot, bbase);
    k_bfill<<<dim3(NBLK, 8), 256, 0, stream>>>(u2i_row, u2i_col, i2u_row, i2u_col, cnt3, bbase, pairbuf);
    k_finalize<<<dim3(NBKT, 8), 256, 0, stream>>>(pairbuf, bbase, btot, csroff, csrcol);
    k_attend<<<dim3(M_NODES * 8 / 8), 256, 0, stream>>>(fbu, fbi, su_src, su_dst,
                                                        si_src, si_dst, csroff, csrcol, out);
}